// Round 5
// baseline (343.713 us; speedup 1.0000x reference)
//
#include <hip/hip_runtime.h>

#define NNODES 50000
#define NEDGES 800000
#define ETOT   850000   /* NEDGES + NNODES self loops */
#define IN_CH  128
#define HID    32
#define C1     128      /* HEADS*HID */
#define NEG    0.2f
#define BNEPS  1e-5f
#define XFB2   1563     /* gemm blocks = ceil(NNODES/32) */
#define HB8    391      /* hist blocks, 2048 edges each = ceil(NEDGES/2048) */
#define XFEB   1955     /* k_xf_eh grid = 5*HB8 (1:4 hist:gemm interleave) */
#define WTS    160      /* WT row stride in bf16 (320B) */
#define XSS    136      /* xs LDS row stride in bf16 */
#define NC     16       /* histogram replication factor */
#define SCB    196      /* scan blocks = ceil(NNODES/256) */
#define FEB    782      /* k_fill edge blocks (1024 edges each) */
#define FLB    49       /* k_fill self-loop blocks (1024 nodes each) */
#define EB1    2048     /* k_edge1 persistent blocks */
#define EB2    2048     /* k_edge2 persistent blocks */
#define L2E    1.4426950408889634f

#if defined(__has_builtin)
#if __has_builtin(__builtin_amdgcn_exp2f)
#define EXP2F(x) __builtin_amdgcn_exp2f(x)
#endif
#endif
#ifndef EXP2F
#define EXP2F(x) exp2f(x)
#endif

typedef __attribute__((ext_vector_type(8))) short short8;
typedef __attribute__((ext_vector_type(4))) float f32x4;

// fp32 -> bf16 (RNE)
__device__ __forceinline__ unsigned short bf16r(float f) {
    unsigned u = __float_as_uint(f);
    return (unsigned short)((u + 0x7fffu + ((u >> 16) & 1u)) >> 16);
}
__device__ __forceinline__ unsigned bf16pair(float f0, float f1) {
    return (unsigned)bf16r(f0) | ((unsigned)bf16r(f1) << 16);
}
__device__ __forceinline__ float blo(unsigned u) { return __uint_as_float(u << 16); }
__device__ __forceinline__ float bhi(unsigned u) { return __uint_as_float(u & 0xffff0000u); }

__device__ __forceinline__ float4 shfl_xor4(float4 v, int m) {
    return make_float4(__shfl_xor(v.x, m), __shfl_xor(v.y, m),
                       __shfl_xor(v.z, m), __shfl_xor(v.w, m));
}
__device__ __forceinline__ float4 sel4(bool c, float4 a, float4 b) {
    return make_float4(c ? a.x : b.x, c ? a.y : b.y, c ? a.z : b.z, c ? a.w : b.w);
}
__device__ __forceinline__ float4 add4(float4 a, float4 b) {
    return make_float4(a.x + b.x, a.y + b.y, a.z + b.z, a.w + b.w);
}

// 256-thread block inclusive scan (4 waves, shfl_up + LDS wave offsets)
__device__ __forceinline__ int block_iscan(int v, int* ls) {
    int lane = threadIdx.x & 63, w = threadIdx.x >> 6;
    #pragma unroll
    for (int o = 1; o < 64; o <<= 1) {
        int t = __shfl_up(v, o);
        if (lane >= o) v += t;
    }
    if (lane == 63) ls[w] = v;
    __syncthreads();
    int add = 0;
    #pragma unroll
    for (int i = 0; i < 4; i++) add += (i < w) ? ls[i] : 0;
    return v + add;
}

// ---------------- prep: bf16 weights, BN fold, swizzled W2cat, zero HIST ----
// WC layout (bf16, 128 rows x 64 cols): element [ch][c] stored at
// ch*64 + (c&7) + 8*((c>>3) ^ ((ch>>3)&7))  -- chunk-XOR bank swizzle.
__global__ __launch_bounds__(256) void k_prep(const float* __restrict__ Wl1,
                                              const float* __restrict__ Wr1,
                                              const float* __restrict__ Wl2,
                                              const float* __restrict__ Wr2,
                                              const float* __restrict__ bias1,
                                              const float* __restrict__ g1,
                                              const float* __restrict__ b1,
                                              const float* __restrict__ m1,
                                              const float* __restrict__ v1,
                                              unsigned short* __restrict__ WT,
                                              unsigned short* __restrict__ WC,
                                              float* __restrict__ A1,
                                              float* __restrict__ B1,
                                              int* __restrict__ hist,
                                              float* __restrict__ meanbuf) {
    int idx = blockIdx.x * 256 + threadIdx.x;     // 160 blocks -> 40960
    if (idx == 0) meanbuf[0] = 0.f;
    if (blockIdx.x == 0 && threadIdx.x < 128) {   // BN1 fold
        int c = threadIdx.x;
        float sc = g1[c] * rsqrtf(v1[c] + BNEPS);
        A1[c] = sc;
        B1[c] = (bias1[c] - m1[c]) * sc + b1[c];
    }
    for (int i = idx; i < NC * NNODES; i += 160 * 256) hist[i] = 0;  // coalesced zero
    if (idx < 32768) {
        int mat = idx >> 14, rem = idx & 16383;
        int k = rem >> 7, n = rem & 127;
        float v = mat ? Wr1[k * 128 + n] : Wl1[k * 128 + n];
        WT[(size_t)(mat * 128 + n) * WTS + k] = bf16r(v);
    } else {
        int i2 = idx - 32768;                      // 8192 elements -> WC
        int mat = i2 >> 12, rem = i2 & 4095;
        int k = rem >> 5, n = rem & 31;            // k = ch, n = col within mat
        float v = mat ? Wr2[k * 32 + n] : Wl2[k * 32 + n];
        int c = mat * 32 + n;
        int phys = (c >> 3) ^ ((k >> 3) & 7);
        WC[k * 64 + (c & 7) + 8 * phys] = bf16r(v);
    }
}

// ---------------- fused & INTERLEAVED: conv1 MFMA GEMM + histogram ----------
__global__ __launch_bounds__(256) void k_xf_eh(
    const float* __restrict__ x,
    const float* __restrict__ bl, const float* __restrict__ br,
    const unsigned short* __restrict__ WT,
    unsigned* __restrict__ xlb, float* __restrict__ xr,
    const int* __restrict__ ei, const float* __restrict__ ea,
    int* __restrict__ hist, int* __restrict__ eoff,
    float* __restrict__ meanbuf) {
    __shared__ short xs_s[64 * XSS];              // rows 0-31 hi, 32-63 lo
    int bi = blockIdx.x;
    if (bi % 5 == 0) {
        // ---- histogram (replicated) + edge_attr mean + slot offset ----
        float* ls = (float*)xs_s;
        int hb = bi / 5;                           // 0..390
        int e0 = hb * 2048 + threadIdx.x;
        float v = 0.f;
        if (hb < HB8 - 1) {                        // full block: no bounds checks
            #pragma unroll
            for (int j = 0; j < 8; j++) {
                int e = e0 + 256 * j;
                int c = (8 * hb + j) & (NC - 1);   // = (e>>8)&15, matches k_fill
                eoff[e] = atomicAdd(&hist[c * NNODES + ei[NEDGES + e]], 1);
                v += ea[e];
            }
        } else {
            #pragma unroll
            for (int j = 0; j < 8; j++) {
                int e = e0 + 256 * j;
                if (e < NEDGES) {
                    int c = (8 * hb + j) & (NC - 1);
                    eoff[e] = atomicAdd(&hist[c * NNODES + ei[NEDGES + e]], 1);
                    v += ea[e];
                }
            }
        }
        #pragma unroll
        for (int o = 32; o > 0; o >>= 1) v += __shfl_down(v, o, 64);
        if ((threadIdx.x & 63) == 0) ls[threadIdx.x >> 6] = v;
        __syncthreads();
        if (threadIdx.x == 0) atomicAdd(meanbuf, ls[0] + ls[1] + ls[2] + ls[3]);
        return;
    }
    int g = bi - bi / 5 - 1;                       // GEMM ordinal
    if (g >= XFB2) return;
    int n0g = g * 32;
    // ---- stage x tile: 32 nodes x 128 k, bf16 hi + lo ----
    {
        int nd = threadIdx.x >> 3, kc = (threadIdx.x & 7) * 16;
        bool valid = (n0g + nd) < NNODES;
        float xv[16];
        #pragma unroll
        for (int i = 0; i < 4; i++) {
            float4 t = valid ? ((const float4*)(x + (size_t)(n0g + nd) * IN_CH + kc))[i]
                             : make_float4(0.f, 0.f, 0.f, 0.f);
            xv[4 * i] = t.x; xv[4 * i + 1] = t.y; xv[4 * i + 2] = t.z; xv[4 * i + 3] = t.w;
        }
        unsigned hi[8], lo[8];
        #pragma unroll
        for (int i = 0; i < 8; i++) {
            unsigned short h0 = bf16r(xv[2 * i]), h1 = bf16r(xv[2 * i + 1]);
            float l0 = xv[2 * i]     - __uint_as_float(((unsigned)h0) << 16);
            float l1 = xv[2 * i + 1] - __uint_as_float(((unsigned)h1) << 16);
            hi[i] = (unsigned)h0 | ((unsigned)h1 << 16);
            lo[i] = bf16pair(l0, l1);
        }
        uint4* ph = (uint4*)&xs_s[nd * XSS + kc];
        ph[0] = make_uint4(hi[0], hi[1], hi[2], hi[3]);
        ph[1] = make_uint4(hi[4], hi[5], hi[6], hi[7]);
        uint4* pl = (uint4*)&xs_s[(nd + 32) * XSS + kc];
        pl[0] = make_uint4(lo[0], lo[1], lo[2], lo[3]);
        pl[1] = make_uint4(lo[4], lo[5], lo[6], lo[7]);
    }
    __syncthreads();
    int lane = threadIdx.x & 63;
    int lm = lane & 15, q = lane >> 4;
    int w = threadIdx.x >> 6;
    int n0 = w * 64;                               // this wave's 64 output cols
    f32x4 acc[2][4];
    #pragma unroll
    for (int mt = 0; mt < 2; mt++)
        #pragma unroll
        for (int nt = 0; nt < 4; nt++) acc[mt][nt] = (f32x4)0.f;

    #pragma unroll
    for (int ks = 0; ks < 4; ks++) {
        int k0 = ks * 32 + q * 8;
        short8 ah0 = *(const short8*)&xs_s[(lm)      * XSS + k0];
        short8 ah1 = *(const short8*)&xs_s[(16 + lm) * XSS + k0];
        short8 al0 = *(const short8*)&xs_s[(32 + lm) * XSS + k0];
        short8 al1 = *(const short8*)&xs_s[(48 + lm) * XSS + k0];
        #pragma unroll
        for (int nt = 0; nt < 4; nt++) {
            short8 bfr = *(const short8*)(WT + (size_t)(n0 + nt * 16 + lm) * WTS + k0);
            acc[0][nt] = __builtin_amdgcn_mfma_f32_16x16x32_bf16(al0, bfr, acc[0][nt], 0, 0, 0);
            acc[0][nt] = __builtin_amdgcn_mfma_f32_16x16x32_bf16(ah0, bfr, acc[0][nt], 0, 0, 0);
            acc[1][nt] = __builtin_amdgcn_mfma_f32_16x16x32_bf16(al1, bfr, acc[1][nt], 0, 0, 0);
            acc[1][nt] = __builtin_amdgcn_mfma_f32_16x16x32_bf16(ah1, bfr, acc[1][nt], 0, 0, 0);
        }
    }
    // ---- epilogue: D row=(q*4+reg), col=lm ----
    if (w < 2) {
        #pragma unroll
        for (int nt = 0; nt < 4; nt++) {
            int ch = n0 + nt * 16 + lm;
            float bv = bl[ch];
            #pragma unroll
            for (int mt = 0; mt < 2; mt++)
                #pragma unroll
                for (int r = 0; r < 4; r++) {
                    int node = n0g + mt * 16 + q * 4 + r;
                    float val = acc[mt][nt][r] + bv;
                    float pv = __shfl_xor(val, 1);
                    if ((lm & 1) == 0 && node < NNODES)
                        xlb[(size_t)node * 64 + (ch >> 1)] = bf16pair(val, pv);
                }
        }
    } else {
        #pragma unroll
        for (int nt = 0; nt < 4; nt++) {
            int ch = n0 - 128 + nt * 16 + lm;
            float bv = br[ch];
            #pragma unroll
            for (int mt = 0; mt < 2; mt++)
                #pragma unroll
                for (int r = 0; r < 4; r++) {
                    int node = n0g + mt * 16 + q * 4 + r;
                    if (node < NNODES)
                        xr[(size_t)node * C1 + ch] = acc[mt][nt][r] + bv;
                }
        }
    }
}

// ---------------- reduce 16 histogram copies -> DEG + per-block sums --------
__global__ __launch_bounds__(256) void k_red(int* __restrict__ hist,
                                             int* __restrict__ deg,
                                             int* __restrict__ bsum) {
    __shared__ int ls[4];
    int d = blockIdx.x * 256 + threadIdx.x;
    int s = 0;
    if (d < NNODES) {
        #pragma unroll
        for (int c = 0; c < NC; c++) {
            int v = hist[c * NNODES + d];
            hist[c * NNODES + d] = s;
            s += v;
        }
        deg[d] = s;
    }
    int v = (d < NNODES) ? s + 1 : 0;              // +1 = self loop
    #pragma unroll
    for (int o = 32; o > 0; o >>= 1) v += __shfl_down(v, o, 64);
    if ((threadIdx.x & 63) == 0) ls[threadIdx.x >> 6] = v;
    __syncthreads();
    if (threadIdx.x == 0) bsum[blockIdx.x] = ls[0] + ls[1] + ls[2] + ls[3];
}

// ---------------- rowptr: inline bsum scan + in-block exclusive scan --------
__global__ __launch_bounds__(256) void k_rowp(const int* __restrict__ deg,
                                              const int* __restrict__ bsum,
                                              int* __restrict__ rowptr) {
    __shared__ int ls[4];
    int t = threadIdx.x;
    int bv = (t < SCB) ? bsum[t] : 0;
    int bincl = block_iscan(bv, ls);
    __shared__ int boffs[256];
    boffs[t] = bincl - bv;
    __syncthreads();
    int base = boffs[blockIdx.x];
    __syncthreads();                               // ls reuse barrier
    int d = blockIdx.x * 256 + t;
    int v = (d < NNODES) ? deg[d] + 1 : 0;
    int incl = block_iscan(v, ls);
    if (d < NNODES) rowptr[d] = base + incl - v;
    if (d == NNODES - 1) rowptr[NNODES] = base + incl;
}

// ---------------- CSR fill: ATOMIC-FREE, 4 elements/thread ------------------
__global__ __launch_bounds__(256) void k_fill(const int* __restrict__ ei,
                                              const float* __restrict__ ea,
                                              const int* __restrict__ rowptr,
                                              const float* __restrict__ meanbuf,
                                              const int* __restrict__ hist,
                                              const int* __restrict__ eoff,
                                              unsigned* __restrict__ cpack) {
    int blk = blockIdx.x, tid = threadIdx.x;
    if (blk < FEB) {
        int e0 = blk * 1024 + tid;
        int d[4], sv[4], rp[4], hs[4], eo[4];
        float av[4];
        bool ok[4];
        #pragma unroll
        for (int j = 0; j < 4; j++) {
            int e = e0 + 256 * j;
            ok[j] = e < NEDGES;
            int es = ok[j] ? e : 0;
            d[j]  = ei[NEDGES + es];
            sv[j] = ei[es];
            av[j] = ea[es];
            eo[j] = eoff[es];
        }
        #pragma unroll
        for (int j = 0; j < 4; j++) {
            int e = e0 + 256 * j;
            int c = (e >> 8) & (NC - 1);
            rp[j] = rowptr[d[j]];
            hs[j] = hist[c * NNODES + d[j]];
        }
        #pragma unroll
        for (int j = 0; j < 4; j++)
            if (ok[j])
                cpack[rp[j] + 1 + hs[j] + eo[j]] =
                    ((unsigned)bf16r(av[j]) << 16) | (unsigned)sv[j];
        return;
    }
    if (blk < FEB + FLB) {
        float mv = meanbuf[0] * (1.0f / NEDGES);
        unsigned mp = ((unsigned)bf16r(mv)) << 16;
        int i0 = (blk - FEB) * 1024 + tid;
        int rp[4];
        bool ok[4];
        #pragma unroll
        for (int j = 0; j < 4; j++) {
            int i = i0 + 256 * j;
            ok[j] = i < NNODES;
            rp[j] = rowptr[ok[j] ? i : 0];
        }
        #pragma unroll
        for (int j = 0; j < 4; j++)
            if (ok[j]) cpack[rp[j]] = mp | (unsigned)(i0 + 256 * j);
        return;
    }
    if (tid < 64) cpack[ETOT + tid] = 0u;          // pad for prefetch overrun
}

// ---------------- conv1 edge phase FUSED with BN+ReLU + h@(Wl2|Wr2) ---------
// Persistent waves, decoupled sc/xv pipelines. After the slot merge every
// lane holds the full attention output for its 8 channels; the epilogue
// finishes BN+ReLU (A1/B1 fold) and the 128->64 matvec in-register:
// per-lane partials over 16 output cols (W2cat bf16 in LDS, chunk-XOR
// swizzled), then a 4-stage reduce-scatter across the 16 q-lanes; the
// final lane owns col c = 16s + brev4(q) and writes xlb2/xr2 directly.
// OUT1 and the k_epi kernel are eliminated.
__global__ __launch_bounds__(256) void k_edge1(
    const unsigned* __restrict__ xlb, const float* __restrict__ xr,
    const int* __restrict__ rowptr, const unsigned* __restrict__ cpack,
    const float* __restrict__ We, const float* __restrict__ att,
    const float* __restrict__ A1, const float* __restrict__ B1,
    const unsigned short* __restrict__ WC,
    const float* __restrict__ bl2, const float* __restrict__ br2,
    unsigned* __restrict__ xlb2, float* __restrict__ xr2) {
    __shared__ unsigned short Wlds[8192];          // 128 x 64 bf16, swizzled
    {
        uint4* dst = (uint4*)Wlds;
        const uint4* src = (const uint4*)WC;
        #pragma unroll
        for (int i = 0; i < 4; i++) dst[threadIdx.x + 256 * i] = src[threadIdx.x + 256 * i];
    }
    __syncthreads();
    int lane = threadIdx.x & 63;
    int q = lane & 15, s = lane >> 4;
    int node = blockIdx.x * 4 + (threadIdx.x >> 6);  // < 8192 < NNODES always
    const int W = EB1 * 4;
    const float C6 = 0.6f * L2E, C4 = 0.4f * L2E;
    float4 we0 = ((const float4*)We)[2 * q],  we1 = ((const float4*)We)[2 * q + 1];
    float4 av0 = ((const float4*)att)[2 * q], av1 = ((const float4*)att)[2 * q + 1];
    float4 aA0 = make_float4(av0.x * C6, av0.y * C6, av0.z * C6, av0.w * C6);
    float4 aB0 = make_float4(av0.x * C4, av0.y * C4, av0.z * C4, av0.w * C4);
    float4 aA1 = make_float4(av1.x * C6, av1.y * C6, av1.z * C6, av1.w * C6);
    float4 aB1 = make_float4(av1.x * C4, av1.y * C4, av1.z * C4, av1.w * C4);
    float4 A80 = ((const float4*)A1)[2 * q], A81 = ((const float4*)A1)[2 * q + 1];
    float4 B80 = ((const float4*)B1)[2 * q], B81 = ((const float4*)B1)[2 * q + 1];
    int brev = ((q & 1) << 3) | ((q & 2) << 1) | ((q & 4) >> 1) | ((q & 8) >> 3);
    int ocol = 16 * s + brev;                      // this lane's output col
    float bcv = (s < 2) ? bl2[ocol] : br2[ocol - 32];
    const uint4* xlv = (const uint4*)xlb;          // row = 16 uint4 (128 ch)
    int r0 = rowptr[node], r1 = rowptr[node + 1];
    float4 xr0 = ((const float4*)xr)[(size_t)node * 32 + 2 * q];
    float4 xr1 = ((const float4*)xr)[(size_t)node * 32 + 2 * q + 1];
    for (;;) {
        int nn = node + W;
        bool more = nn < NNODES;
        int nr0 = 0, nr1 = 0;
        float4 nxr0 = make_float4(0.f, 0.f, 0.f, 0.f);
        float4 nxr1 = make_float4(0.f, 0.f, 0.f, 0.f);
        if (more) {                                // prefetch next node
            nr0 = rowptr[nn]; nr1 = rowptr[nn + 1];
            nxr0 = ((const float4*)xr)[(size_t)nn * 32 + 2 * q];
            nxr1 = ((const float4*)xr)[(size_t)nn * 32 + 2 * q + 1];
        }
        float den = 0.f;
        float a0 = 0.f, a1 = 0.f, a2 = 0.f, a3 = 0.f;
        float a4 = 0.f, a5 = 0.f, a6 = 0.f, a7 = 0.f;
        int nit = (r1 - r0 + 3) >> 2;
        int k = r0 + s;
        unsigned sc0 = cpack[k];                   // sc ring (padded: safe)
        unsigned sc1 = cpack[k + 4];
        unsigned sc2 = cpack[k + 8];
        unsigned sc3 = cpack[k + 12];
        unsigned sc4 = cpack[k + 16];
        uint4 xv0 = xlv[(size_t)(sc0 & 0xffffu) * 16 + q];
        uint4 xv1 = xlv[(size_t)(sc1 & 0xffffu) * 16 + q];
        uint4 xv2 = xlv[(size_t)(sc2 & 0xffffu) * 16 + q];
        for (int it = 0; it < nit; it++) {
            unsigned scn = cpack[k + 20];                       // sc group it+5
            uint4 xvn = xlv[(size_t)(sc3 & 0xffffu) * 16 + q];  // gather it+3
            bool ok = k < r1;
            float av = __uint_as_float(sc0 & 0xffff0000u);  // bf16 attr
            float x0 = blo(xv0.x), x1 = bhi(xv0.x), x2 = blo(xv0.y), x3 = bhi(xv0.y);
            float x4 = blo(xv0.z), x5 = bhi(xv0.z), x6 = blo(xv0.w), x7 = bhi(xv0.w);
            float s0 = fmaf(av, we0.x, x0 + xr0.x);
            float s1 = fmaf(av, we0.y, x1 + xr0.y);
            float s2 = fmaf(av, we0.z, x2 + xr0.z);
            float s3 = fmaf(av, we0.w, x3 + xr0.w);
            float s4 = fmaf(av, we1.x, x4 + xr1.x);
            float s5 = fmaf(av, we1.y, x5 + xr1.y);
            float s6 = fmaf(av, we1.z, x6 + xr1.z);
            float s7 = fmaf(av, we1.w, x7 + xr1.w);
            float tA = s0 * aA0.x;            tA = fmaf(fabsf(s0), aB0.x, tA);
            tA = fmaf(s1, aA0.y, tA);         tA = fmaf(fabsf(s1), aB0.y, tA);
            tA = fmaf(s2, aA0.z, tA);         tA = fmaf(fabsf(s2), aB0.z, tA);
            tA = fmaf(s3, aA0.w, tA);         tA = fmaf(fabsf(s3), aB0.w, tA);
            float tB = s4 * aA1.x;            tB = fmaf(fabsf(s4), aB1.x, tB);
            tB = fmaf(s5, aA1.y, tB);         tB = fmaf(fabsf(s5), aB1.y, tB);
            tB = fmaf(s6, aA1.z, tB);         tB = fmaf(fabsf(s6), aB1.z, tB);
            tB = fmaf(s7, aA1.w, tB);         tB = fmaf(fabsf(s7), aB1.w, tB);
            float t = tA + tB;
            t += __shfl_xor(t, 1);
            t += __shfl_xor(t, 2);                 // 4-lane group = this lane's head
            float e = ok ? EXP2F(t) : 0.f;
            den += e;
            a0 = fmaf(e, x0, a0); a1 = fmaf(e, x1, a1);
            a2 = fmaf(e, x2, a2); a3 = fmaf(e, x3, a3);
            a4 = fmaf(e, x4, a4); a5 = fmaf(e, x5, a5);
            a6 = fmaf(e, x6, a6); a7 = fmaf(e, x7, a7);
            k += 4;
            sc0 = sc1; sc1 = sc2; sc2 = sc3; sc3 = sc4; sc4 = scn;
            xv0 = xv1; xv1 = xv2; xv2 = xvn;
        }
        // merge the 4 slots -> all lanes hold full sums for their channels
        #pragma unroll
        for (int o = 16; o <= 32; o <<= 1) {
            den += __shfl_xor(den, o);
            a0 += __shfl_xor(a0, o); a1 += __shfl_xor(a1, o);
            a2 += __shfl_xor(a2, o); a3 += __shfl_xor(a3, o);
            a4 += __shfl_xor(a4, o); a5 += __shfl_xor(a5, o);
            a6 += __shfl_xor(a6, o); a7 += __shfl_xor(a7, o);
        }
        // ---- fused BN + ReLU ----
        float rd = 1.f / den;
        float h[8];
        h[0] = fmaxf(fmaf(a0 * rd, A80.x, B80.x), 0.f);
        h[1] = fmaxf(fmaf(a1 * rd, A80.y, B80.y), 0.f);
        h[2] = fmaxf(fmaf(a2 * rd, A80.z, B80.z), 0.f);
        h[3] = fmaxf(fmaf(a3 * rd, A80.w, B80.w), 0.f);
        h[4] = fmaxf(fmaf(a4 * rd, A81.x, B81.x), 0.f);
        h[5] = fmaxf(fmaf(a5 * rd, A81.y, B81.y), 0.f);
        h[6] = fmaxf(fmaf(a6 * rd, A81.z, B81.z), 0.f);
        h[7] = fmaxf(fmaf(a7 * rd, A81.w, B81.w), 0.f);
        // ---- matvec partials: lane (q,s) -> outputs 16s..16s+15 ----
        float4 pA = make_float4(0.f, 0.f, 0.f, 0.f), pB = pA, pC = pA, pD = pA;
        #pragma unroll
        for (int j = 0; j < 8; j++) {
            int row = 8 * q + j;
            int ph0 = (2 * s) ^ (q & 7);
            uint4 w0 = ((const uint4*)Wlds)[row * 8 + ph0];        // cols 16s..16s+7
            uint4 w1 = ((const uint4*)Wlds)[row * 8 + (ph0 ^ 1)];  // cols 16s+8..15
            float hj = h[j];
            pA.x = fmaf(hj, blo(w0.x), pA.x); pA.y = fmaf(hj, bhi(w0.x), pA.y);
            pA.z = fmaf(hj, blo(w0.y), pA.z); pA.w = fmaf(hj, bhi(w0.y), pA.w);
            pB.x = fmaf(hj, blo(w0.z), pB.x); pB.y = fmaf(hj, bhi(w0.z), pB.y);
            pB.z = fmaf(hj, blo(w0.w), pB.z); pB.w = fmaf(hj, bhi(w0.w), pB.w);
            pC.x = fmaf(hj, blo(w1.x), pC.x); pC.y = fmaf(hj, bhi(w1.x), pC.y);
            pC.z = fmaf(hj, blo(w1.y), pC.z); pC.w = fmaf(hj, bhi(w1.y), pC.w);
            pD.x = fmaf(hj, blo(w1.z), pD.x); pD.y = fmaf(hj, bhi(w1.z), pD.y);
            pD.z = fmaf(hj, blo(w1.w), pD.z); pD.w = fmaf(hj, bhi(w1.w), pD.w);
        }
        // ---- reduce-scatter across 16 q-lanes (bit b of col <- q bit 3-b) ----
        float4 kA = sel4(q & 1, pC, pA), kB = sel4(q & 1, pD, pB);
        float4 sA_ = sel4(q & 1, pA, pC), sB_ = sel4(q & 1, pB, pD);
        kA = add4(kA, shfl_xor4(sA_, 1)); kB = add4(kB, shfl_xor4(sB_, 1));
        float4 k2 = sel4(q & 2, kB, kA);
        float4 s2_ = sel4(q & 2, kA, kB);
        k2 = add4(k2, shfl_xor4(s2_, 2));
        float v0 = (q & 4) ? k2.z : k2.x, v1 = (q & 4) ? k2.w : k2.y;
        float u0 = (q & 4) ? k2.x : k2.z, u1 = (q & 4) ? k2.y : k2.w;
        v0 += __shfl_xor(u0, 4); v1 += __shfl_xor(u1, 4);
        float vf = (q & 8) ? v1 : v0;
        float uf = (q & 8) ? v0 : v1;
        float val = vf + __shfl_xor(uf, 8) + bcv;  // output col = ocol
        if (s < 2) {                               // Wl2 cols -> xlb2 bf16 pairs
            float pv = __shfl_xor(val, 8);         // partner holds ocol^1
            if ((q & 8) == 0)
                xlb2[(size_t)node * 16 + (ocol >> 1)] = bf16pair(val, pv);
        } else {                                   // Wr2 cols -> xr2 f32
            xr2[(size_t)node * HID + (ocol - 32)] = val;
        }
        if (!more) return;
        node = nn; r0 = nr0; r1 = nr1; xr0 = nxr0; xr1 = nxr1;
    }
}

// ---------------- conv2 fused edge phase + BN + classifier ------------------
__global__ __launch_bounds__(256) void k_edge2(
    const unsigned* __restrict__ xlb2, const float* __restrict__ xr2,
    const int* __restrict__ rowptr, const unsigned* __restrict__ cpack,
    const float* __restrict__ We2, const float* __restrict__ att2,
    const float* __restrict__ bias2,
    const float* __restrict__ g2, const float* __restrict__ b2,
    const float* __restrict__ m2, const float* __restrict__ v2,
    const float* __restrict__ W, const float* __restrict__ b,
    float* __restrict__ y) {
    int lane = threadIdx.x & 63;
    int q = lane & 7, s = lane >> 3;
    int node = blockIdx.x * 4 + (threadIdx.x >> 6);
    if (node >= NNODES) return;
    const int WV = EB2 * 4;
    const float C6 = 0.6f * L2E, C4 = 0.4f * L2E;
    float4 we = ((const float4*)We2)[q];
    float4 av4 = ((const float4*)att2)[q];
    float4 aA = make_float4(av4.x * C6, av4.y * C6, av4.z * C6, av4.w * C6);
    float4 aB = make_float4(av4.x * C4, av4.y * C4, av4.z * C4, av4.w * C4);
    float4 gv = ((const float4*)g2)[q];
    float4 bv = ((const float4*)b2)[q];
    float4 mv = ((const float4*)m2)[q];
    float4 vv = ((const float4*)v2)[q];
    float4 bi = ((const float4*)bias2)[q];
    float4 sA, sB;
    sA.x = gv.x * rsqrtf(vv.x + BNEPS); sB.x = (bi.x - mv.x) * sA.x + bv.x;
    sA.y = gv.y * rsqrtf(vv.y + BNEPS); sB.y = (bi.y - mv.y) * sA.y + bv.y;
    sA.z = gv.z * rsqrtf(vv.z + BNEPS); sB.z = (bi.z - mv.z) * sA.z + bv.z;
    sA.w = gv.w * rsqrtf(vv.w + BNEPS); sB.w = (bi.w - mv.w) * sA.w + bv.w;
    float4 w0 = ((const float4*)W)[2 * q];         // ch 4q,4q+1 x {out0,out1}
    float4 w1 = ((const float4*)W)[2 * q + 1];     // ch 4q+2,4q+3
    float bb0 = b[0], bb1 = b[1];
    const uint2* xlv = (const uint2*)xlb2;         // row = 8 uint2 (32 ch)
    int r0 = rowptr[node], r1 = rowptr[node + 1];
    float4 xr0 = ((const float4*)xr2)[(size_t)node * 8 + q];
    for (;;) {
        int nn = node + WV;
        bool more = nn < NNODES;
        int nr0 = 0, nr1 = 0;
        float4 nxr0 = make_float4(0.f, 0.f, 0.f, 0.f);
        if (more) {                                // prefetch next node
            nr0 = rowptr[nn]; nr1 = rowptr[nn + 1];
            nxr0 = ((const float4*)xr2)[(size_t)nn * 8 + q];
        }
        float den = 0.f;
        float a0 = 0.f, a1 = 0.f, a2 = 0.f, a3 = 0.f;
        int nit = (r1 - r0 + 7) >> 3;
        int k = r0 + s;
        unsigned sc0 = cpack[k];
        unsigned sc1 = cpack[k + 8];
        unsigned sc2 = cpack[k + 16];
        unsigned sc3 = cpack[k + 24];
        unsigned sc4 = cpack[k + 32];
        uint2 xv0 = xlv[(size_t)(sc0 & 0xffffu) * 8 + q];
        uint2 xv1 = xlv[(size_t)(sc1 & 0xffffu) * 8 + q];
        uint2 xv2 = xlv[(size_t)(sc2 & 0xffffu) * 8 + q];
        for (int it = 0; it < nit; it++) {
            unsigned scn = cpack[k + 40];                      // sc group it+5
            uint2 xvn = xlv[(size_t)(sc3 & 0xffffu) * 8 + q];  // gather it+3
            bool ok = k < r1;
            float av = __uint_as_float(sc0 & 0xffff0000u);
            float x0 = blo(xv0.x), x1 = bhi(xv0.x), x2 = blo(xv0.y), x3 = bhi(xv0.y);
            float s0 = fmaf(av, we.x, x0 + xr0.x);
            float s1 = fmaf(av, we.y, x1 + xr0.y);
            float s2 = fmaf(av, we.z, x2 + xr0.z);
            float s3 = fmaf(av, we.w, x3 + xr0.w);
            float tA = s0 * aA.x;             tA = fmaf(fabsf(s0), aB.x, tA);
            tA = fmaf(s1, aA.y, tA);          tA = fmaf(fabsf(s1), aB.y, tA);
            float tB = s2 * aA.z;             tB = fmaf(fabsf(s2), aB.z, tB);
            tB = fmaf(s3, aA.w, tB);          tB = fmaf(fabsf(s3), aB.w, tB);
            float t = tA + tB;
            t += __shfl_xor(t, 1);
            t += __shfl_xor(t, 2);
            t += __shfl_xor(t, 4);                 // 8-lane group = full logit
            float e = ok ? EXP2F(t) : 0.f;
            den += e;
            a0 = fmaf(e, x0, a0); a1 = fmaf(e, x1, a1);
            a2 = fmaf(e, x2, a2); a3 = fmaf(e, x3, a3);
            k += 8;
            sc0 = sc1; sc1 = sc2; sc2 = sc3; sc3 = sc4; sc4 = scn;
            xv0 = xv1; xv1 = xv2; xv2 = xvn;
        }
        #pragma unroll
        for (int o = 8; o <= 32; o <<= 1) {        // merge 8 slots
            den += __shfl_xor(den, o);
            a0 += __shfl_xor(a0, o); a1 += __shfl_xor(a1, o);
            a2 += __shfl_xor(a2, o); a3 += __shfl_xor(a3, o);
        }
        float rd = 1.f / den;
        float h0 = fmaxf(fmaf(a0 * rd, sA.x, sB.x), 0.f);
        float h1 = fmaxf(fmaf(a1 * rd, sA.y, sB.y), 0.f);
        float h2 = fmaxf(fmaf(a2 * rd, sA.z, sB.z), 0.f);
        float h3 = fmaxf(fmaf(a3 * rd, sA.w, sB.w), 0.f);
        float u0 = h0 * w0.x + h1 * w0.z + h2 * w1.x + h3 * w1.z;
        float u1 = h0 * w0.y + h1 * w0.w + h2 * w1.y + h3 * w1.w;
        u0 += __shfl_xor(u0, 1); u0 += __shfl_xor(u0, 2); u0 += __shfl_xor(u0, 4);
        u1 += __shfl_xor(u1, 1); u1 += __shfl_xor(u1, 2); u1 += __shfl_xor(u1, 4);
        if (lane == 0) {
            y[(size_t)node * 2]     = u0 + bb0;
            y[(size_t)node * 2 + 1] = u1 + bb1;
        }
        if (!more) return;
        node = nn; r0 = nr0; r1 = nr1; xr0 = nxr0;
    }
}

extern "C" void kernel_launch(void* const* d_in, const int* in_sizes, int n_in,
                              void* d_out, int out_size, void* d_ws, size_t ws_size,
                              hipStream_t stream) {
    const float* x       = (const float*)d_in[0];
    const int*   ei      = (const int*)d_in[1];
    const float* ea      = (const float*)d_in[2];
    const float* c1_Wl   = (const float*)d_in[3];
    const float* c1_bl   = (const float*)d_in[4];
    const float* c1_Wr   = (const float*)d_in[5];
    const float* c1_br   = (const float*)d_in[6];
    const float* c1_We   = (const float*)d_in[7];
    const float* c1_att  = (const float*)d_in[8];
    const float* c1_bias = (const float*)d_in[9];
    const float* bn1_g   = (const float*)d_in[10];
    const float* bn1_b   = (const float*)d_in[11];
    const float* bn1_m   = (const float*)d_in[12];
    const float* bn1_v   = (const float*)d_in[13];
    const float* c2_Wl   = (const float*)d_in[14];
    const float* c2_bl   = (const float*)d_in[15];
    const float* c2_Wr   = (const float*)d_in[16];
    const float* c2_br   = (const float*)d_in[17];
    const float* c2_We   = (const float*)d_in[18];
    const float* c2_att  = (const float*)d_in[19];
    const float* c2_bias = (const float*)d_in[20];
    const float* bn2_g   = (const float*)d_in[21];
    const float* bn2_b   = (const float*)d_in[22];
    const float* bn2_m   = (const float*)d_in[23];
    const float* bn2_v   = (const float*)d_in[24];
    const float* clf_W   = (const float*)d_in[25];
    const float* clf_b   = (const float*)d_in[26];

    float* ws = (float*)d_ws;
    size_t off = 0;
    unsigned* XLb  = (unsigned*)(ws + off); off += (size_t)NNODES * 64;  // bf16x2
    float*    XR1  = ws + off; off += (size_t)NNODES * C1;
    unsigned* XLb2 = (unsigned*)(ws + off); off += (size_t)NNODES * 16;  // bf16x2
    float*    XR2  = ws + off; off += (size_t)NNODES * HID;
    unsigned* CPACK= (unsigned*)(ws + off); off += (size_t)ETOT + 64;    // 4B/edge
    unsigned short* WT = (unsigned short*)(ws + off); off += 256 * WTS / 2;
    unsigned short* WC = (unsigned short*)(ws + off); off += 4096;       // 128x64 bf16
    float*    A1v  = ws + off; off += 128;
    float*    B1v  = ws + off; off += 128;
    int*      EOFF = (int*)(ws + off); off += NEDGES;
    int*      ROWP = (int*)(ws + off); off += NNODES + 16;
    int*      DEG  = (int*)(ws + off); off += NNODES;
    int*      BSUM = (int*)(ws + off); off += 256;
    int*      HIST = (int*)(ws + off); off += (size_t)NC * NNODES;  // zeroed by k_prep
    float*    MEANB= ws + off; off += 64;
    if (ws_size < off * sizeof(float)) return;  // workspace too small: fail loudly

    k_prep  <<<160, 256, 0, stream>>>(c1_Wl, c1_Wr, c2_Wl, c2_Wr,
                                      c1_bias, bn1_g, bn1_b, bn1_m, bn1_v,
                                      WT, WC, A1v, B1v, HIST, MEANB);
    k_xf_eh <<<XFEB, 256, 0, stream>>>(x, c1_bl, c1_br, WT, XLb, XR1,
                                       ei, ea, HIST, EOFF, MEANB);
    k_red   <<<SCB, 256, 0, stream>>>(HIST, DEG, BSUM);
    k_rowp  <<<SCB, 256, 0, stream>>>(DEG, BSUM, ROWP);
    k_fill  <<<FEB + FLB + 1, 256, 0, stream>>>(ei, ea, ROWP, MEANB, HIST, EOFF, CPACK);
    k_edge1 <<<EB1, 256, 0, stream>>>(XLb, XR1, ROWP, CPACK, c1_We, c1_att,
                                      A1v, B1v, WC, c2_bl, c2_br, XLb2, XR2);
    k_edge2 <<<EB2, 256, 0, stream>>>(XLb2, XR2, ROWP, CPACK, c2_We, c2_att,
                                      c2_bias, bn2_g, bn2_b, bn2_m, bn2_v,
                                      clf_W, clf_b, (float*)d_out);
}

// Round 6
// 292.360 us; speedup vs baseline: 1.1756x; 1.1756x over previous
//
#include <hip/hip_runtime.h>

#define NNODES 50000
#define NEDGES 800000
#define ETOT   850000   /* NEDGES + NNODES self loops */
#define IN_CH  128
#define HID    32
#define C1     128      /* HEADS*HID */
#define NEG    0.2f
#define BNEPS  1e-5f
#define XFB2   1563     /* gemm blocks = ceil(NNODES/32) */
#define HB8    391      /* hist blocks, 2048 edges each = ceil(NEDGES/2048) */
#define XFEB   1955     /* k_xf_eh grid = 5*HB8 (1:4 hist:gemm interleave) */
#define WTS    160      /* WT row stride in bf16 (320B) */
#define XSS    136      /* xs LDS row stride in bf16 */
#define NC     16       /* histogram replication factor */
#define SCB    196      /* scan blocks = ceil(NNODES/256) */
#define FEB    782      /* k_fill edge blocks (1024 edges each) */
#define FLB    49       /* k_fill self-loop blocks (1024 nodes each) */
#define EB1    2048     /* k_edge1 blocks -> 8192 waves */
#define EB2    2048     /* k_edge2 blocks -> 8192 waves */
#define L2E    1.4426950408889634f

#if defined(__has_builtin)
#if __has_builtin(__builtin_amdgcn_exp2f)
#define EXP2F(x) __builtin_amdgcn_exp2f(x)
#endif
#endif
#ifndef EXP2F
#define EXP2F(x) exp2f(x)
#endif

typedef __attribute__((ext_vector_type(8))) short short8;
typedef __attribute__((ext_vector_type(4))) float f32x4;

// fp32 -> bf16 (RNE)
__device__ __forceinline__ unsigned short bf16r(float f) {
    unsigned u = __float_as_uint(f);
    return (unsigned short)((u + 0x7fffu + ((u >> 16) & 1u)) >> 16);
}
__device__ __forceinline__ unsigned bf16pair(float f0, float f1) {
    return (unsigned)bf16r(f0) | ((unsigned)bf16r(f1) << 16);
}
__device__ __forceinline__ float blo(unsigned u) { return __uint_as_float(u << 16); }
__device__ __forceinline__ float bhi(unsigned u) { return __uint_as_float(u & 0xffff0000u); }

// 256-thread block inclusive scan (4 waves, shfl_up + LDS wave offsets)
__device__ __forceinline__ int block_iscan(int v, int* ls) {
    int lane = threadIdx.x & 63, w = threadIdx.x >> 6;
    #pragma unroll
    for (int o = 1; o < 64; o <<= 1) {
        int t = __shfl_up(v, o);
        if (lane >= o) v += t;
    }
    if (lane == 63) ls[w] = v;
    __syncthreads();
    int add = 0;
    #pragma unroll
    for (int i = 0; i < 4; i++) add += (i < w) ? ls[i] : 0;
    return v + add;
}

// ---------------- prep: bf16-transposed weights + zero HIST/MEANB -----------
__global__ __launch_bounds__(256) void k_prep(const float* __restrict__ Wl1,
                                              const float* __restrict__ Wr1,
                                              const float* __restrict__ Wl2,
                                              const float* __restrict__ Wr2,
                                              unsigned short* __restrict__ WT,
                                              unsigned short* __restrict__ WT2,
                                              int* __restrict__ hist,
                                              float* __restrict__ meanbuf) {
    int idx = blockIdx.x * 256 + threadIdx.x;     // 160 blocks -> 40960
    if (idx == 0) meanbuf[0] = 0.f;
    for (int i = idx; i < NC * NNODES; i += 160 * 256) hist[i] = 0;  // coalesced zero
    if (idx < 32768) {
        int mat = idx >> 14, rem = idx & 16383;
        int k = rem >> 7, n = rem & 127;
        float v = mat ? Wr1[k * 128 + n] : Wl1[k * 128 + n];
        WT[(size_t)(mat * 128 + n) * WTS + k] = bf16r(v);
    } else {
        int i2 = idx - 32768;                      // 8192 elements
        int mat = i2 >> 12, rem = i2 & 4095;
        int k = rem >> 5, n = rem & 31;
        float v = mat ? Wr2[k * 32 + n] : Wl2[k * 32 + n];
        WT2[(size_t)(mat * 32 + n) * WTS + k] = bf16r(v);
    }
}

// ---------------- fused & INTERLEAVED: conv1 MFMA GEMM + histogram ----------
__global__ __launch_bounds__(256) void k_xf_eh(
    const float* __restrict__ x,
    const float* __restrict__ bl, const float* __restrict__ br,
    const unsigned short* __restrict__ WT,
    unsigned* __restrict__ xlb, float* __restrict__ xr,
    const int* __restrict__ ei, const float* __restrict__ ea,
    int* __restrict__ hist, int* __restrict__ eoff,
    float* __restrict__ meanbuf) {
    __shared__ short xs_s[64 * XSS];              // rows 0-31 hi, 32-63 lo
    int bi = blockIdx.x;
    if (bi % 5 == 0) {
        // ---- histogram (replicated) + edge_attr mean + slot offset ----
        float* ls = (float*)xs_s;
        int hb = bi / 5;                           // 0..390
        int e0 = hb * 2048 + threadIdx.x;
        float v = 0.f;
        if (hb < HB8 - 1) {                        // full block: no bounds checks
            #pragma unroll
            for (int j = 0; j < 8; j++) {
                int e = e0 + 256 * j;
                int c = (8 * hb + j) & (NC - 1);   // = (e>>8)&15, matches k_fill
                eoff[e] = atomicAdd(&hist[c * NNODES + ei[NEDGES + e]], 1);
                v += ea[e];
            }
        } else {
            #pragma unroll
            for (int j = 0; j < 8; j++) {
                int e = e0 + 256 * j;
                if (e < NEDGES) {
                    int c = (8 * hb + j) & (NC - 1);
                    eoff[e] = atomicAdd(&hist[c * NNODES + ei[NEDGES + e]], 1);
                    v += ea[e];
                }
            }
        }
        #pragma unroll
        for (int o = 32; o > 0; o >>= 1) v += __shfl_down(v, o, 64);
        if ((threadIdx.x & 63) == 0) ls[threadIdx.x >> 6] = v;
        __syncthreads();
        if (threadIdx.x == 0) atomicAdd(meanbuf, ls[0] + ls[1] + ls[2] + ls[3]);
        return;
    }
    int g = bi - bi / 5 - 1;                       // GEMM ordinal
    if (g >= XFB2) return;
    int n0g = g * 32;
    // ---- stage x tile: 32 nodes x 128 k, bf16 hi + lo ----
    {
        int nd = threadIdx.x >> 3, kc = (threadIdx.x & 7) * 16;
        bool valid = (n0g + nd) < NNODES;
        float xv[16];
        #pragma unroll
        for (int i = 0; i < 4; i++) {
            float4 t = valid ? ((const float4*)(x + (size_t)(n0g + nd) * IN_CH + kc))[i]
                             : make_float4(0.f, 0.f, 0.f, 0.f);
            xv[4 * i] = t.x; xv[4 * i + 1] = t.y; xv[4 * i + 2] = t.z; xv[4 * i + 3] = t.w;
        }
        unsigned hi[8], lo[8];
        #pragma unroll
        for (int i = 0; i < 8; i++) {
            unsigned short h0 = bf16r(xv[2 * i]), h1 = bf16r(xv[2 * i + 1]);
            float l0 = xv[2 * i]     - __uint_as_float(((unsigned)h0) << 16);
            float l1 = xv[2 * i + 1] - __uint_as_float(((unsigned)h1) << 16);
            hi[i] = (unsigned)h0 | ((unsigned)h1 << 16);
            lo[i] = bf16pair(l0, l1);
        }
        uint4* ph = (uint4*)&xs_s[nd * XSS + kc];
        ph[0] = make_uint4(hi[0], hi[1], hi[2], hi[3]);
        ph[1] = make_uint4(hi[4], hi[5], hi[6], hi[7]);
        uint4* pl = (uint4*)&xs_s[(nd + 32) * XSS + kc];
        pl[0] = make_uint4(lo[0], lo[1], lo[2], lo[3]);
        pl[1] = make_uint4(lo[4], lo[5], lo[6], lo[7]);
    }
    __syncthreads();
    int lane = threadIdx.x & 63;
    int lm = lane & 15, q = lane >> 4;
    int w = threadIdx.x >> 6;
    int n0 = w * 64;                               // this wave's 64 output cols
    f32x4 acc[2][4];
    #pragma unroll
    for (int mt = 0; mt < 2; mt++)
        #pragma unroll
        for (int nt = 0; nt < 4; nt++) acc[mt][nt] = (f32x4)0.f;

    #pragma unroll
    for (int ks = 0; ks < 4; ks++) {
        int k0 = ks * 32 + q * 8;
        short8 ah0 = *(const short8*)&xs_s[(lm)      * XSS + k0];
        short8 ah1 = *(const short8*)&xs_s[(16 + lm) * XSS + k0];
        short8 al0 = *(const short8*)&xs_s[(32 + lm) * XSS + k0];
        short8 al1 = *(const short8*)&xs_s[(48 + lm) * XSS + k0];
        #pragma unroll
        for (int nt = 0; nt < 4; nt++) {
            short8 bfr = *(const short8*)(WT + (size_t)(n0 + nt * 16 + lm) * WTS + k0);
            acc[0][nt] = __builtin_amdgcn_mfma_f32_16x16x32_bf16(al0, bfr, acc[0][nt], 0, 0, 0);
            acc[0][nt] = __builtin_amdgcn_mfma_f32_16x16x32_bf16(ah0, bfr, acc[0][nt], 0, 0, 0);
            acc[1][nt] = __builtin_amdgcn_mfma_f32_16x16x32_bf16(al1, bfr, acc[1][nt], 0, 0, 0);
            acc[1][nt] = __builtin_amdgcn_mfma_f32_16x16x32_bf16(ah1, bfr, acc[1][nt], 0, 0, 0);
        }
    }
    // ---- epilogue: D row=(q*4+reg), col=lm ----
    if (w < 2) {
        #pragma unroll
        for (int nt = 0; nt < 4; nt++) {
            int ch = n0 + nt * 16 + lm;
            float bv = bl[ch];
            #pragma unroll
            for (int mt = 0; mt < 2; mt++)
                #pragma unroll
                for (int r = 0; r < 4; r++) {
                    int node = n0g + mt * 16 + q * 4 + r;
                    float val = acc[mt][nt][r] + bv;
                    float pv = __shfl_xor(val, 1);
                    if ((lm & 1) == 0 && node < NNODES)
                        xlb[(size_t)node * 64 + (ch >> 1)] = bf16pair(val, pv);
                }
        }
    } else {
        #pragma unroll
        for (int nt = 0; nt < 4; nt++) {
            int ch = n0 - 128 + nt * 16 + lm;
            float bv = br[ch];
            #pragma unroll
            for (int mt = 0; mt < 2; mt++)
                #pragma unroll
                for (int r = 0; r < 4; r++) {
                    int node = n0g + mt * 16 + q * 4 + r;
                    if (node < NNODES)
                        xr[(size_t)node * C1 + ch] = acc[mt][nt][r] + bv;
                }
        }
    }
}

// ---------------- reduce 16 histogram copies -> DEG + per-block sums --------
__global__ __launch_bounds__(256) void k_red(int* __restrict__ hist,
                                             int* __restrict__ deg,
                                             int* __restrict__ bsum) {
    __shared__ int ls[4];
    int d = blockIdx.x * 256 + threadIdx.x;
    int s = 0;
    if (d < NNODES) {
        #pragma unroll
        for (int c = 0; c < NC; c++) {
            int v = hist[c * NNODES + d];
            hist[c * NNODES + d] = s;
            s += v;
        }
        deg[d] = s;
    }
    int v = (d < NNODES) ? s + 1 : 0;              // +1 = self loop
    #pragma unroll
    for (int o = 32; o > 0; o >>= 1) v += __shfl_down(v, o, 64);
    if ((threadIdx.x & 63) == 0) ls[threadIdx.x >> 6] = v;
    __syncthreads();
    if (threadIdx.x == 0) bsum[blockIdx.x] = ls[0] + ls[1] + ls[2] + ls[3];
}

// ---------------- rowptr: inline bsum scan + in-block exclusive scan --------
__global__ __launch_bounds__(256) void k_rowp(const int* __restrict__ deg,
                                              const int* __restrict__ bsum,
                                              int* __restrict__ rowptr) {
    __shared__ int ls[4];
    int t = threadIdx.x;
    int bv = (t < SCB) ? bsum[t] : 0;
    int bincl = block_iscan(bv, ls);
    __shared__ int boffs[256];
    boffs[t] = bincl - bv;
    __syncthreads();
    int base = boffs[blockIdx.x];
    __syncthreads();                               // ls reuse barrier
    int d = blockIdx.x * 256 + t;
    int v = (d < NNODES) ? deg[d] + 1 : 0;
    int incl = block_iscan(v, ls);
    if (d < NNODES) rowptr[d] = base + incl - v;
    if (d == NNODES - 1) rowptr[NNODES] = base + incl;
}

// ---------------- CSR fill: ATOMIC-FREE, 4 elements/thread ------------------
__global__ __launch_bounds__(256) void k_fill(const int* __restrict__ ei,
                                              const float* __restrict__ ea,
                                              const int* __restrict__ rowptr,
                                              const float* __restrict__ meanbuf,
                                              const int* __restrict__ hist,
                                              const int* __restrict__ eoff,
                                              unsigned* __restrict__ cpack) {
    int blk = blockIdx.x, tid = threadIdx.x;
    if (blk < FEB) {
        int e0 = blk * 1024 + tid;
        int d[4], sv[4], rp[4], hs[4], eo[4];
        float av[4];
        bool ok[4];
        #pragma unroll
        for (int j = 0; j < 4; j++) {
            int e = e0 + 256 * j;
            ok[j] = e < NEDGES;
            int es = ok[j] ? e : 0;
            d[j]  = ei[NEDGES + es];
            sv[j] = ei[es];
            av[j] = ea[es];
            eo[j] = eoff[es];
        }
        #pragma unroll
        for (int j = 0; j < 4; j++) {
            int e = e0 + 256 * j;
            int c = (e >> 8) & (NC - 1);
            rp[j] = rowptr[d[j]];
            hs[j] = hist[c * NNODES + d[j]];
        }
        #pragma unroll
        for (int j = 0; j < 4; j++)
            if (ok[j])
                cpack[rp[j] + 1 + hs[j] + eo[j]] =
                    ((unsigned)bf16r(av[j]) << 16) | (unsigned)sv[j];
        return;
    }
    if (blk < FEB + FLB) {
        float mv = meanbuf[0] * (1.0f / NEDGES);
        unsigned mp = ((unsigned)bf16r(mv)) << 16;
        int i0 = (blk - FEB) * 1024 + tid;
        int rp[4];
        bool ok[4];
        #pragma unroll
        for (int j = 0; j < 4; j++) {
            int i = i0 + 256 * j;
            ok[j] = i < NNODES;
            rp[j] = rowptr[ok[j] ? i : 0];
        }
        #pragma unroll
        for (int j = 0; j < 4; j++)
            if (ok[j]) cpack[rp[j]] = mp | (unsigned)(i0 + 256 * j);
        return;
    }
    if (tid < 64) cpack[ETOT + tid] = 0u;          // pad for prefetch overrun
}

// ---------------- conv1 fused edge phase: contiguous per-wave ranges --------
// Wave wid owns nodes [wid*N/8192, (wid+1)*N/8192) -- contiguous, so cpack/
// xr/out1 streams are sequential and r0_next = r1 (one rowptr load/node).
// wid is XCD-chunk swizzled: blocks on XCD x work a contiguous ~6250-node
// window, keeping its cpack/xr slices L2-resident beside the xlb gathers.
// Decoupled sc ring (5) + xv ring (3); lean 48-VGPR body (no fusion: the
// r5 matvec fusion cost 76 VGPRs -> half occupancy -> 2x dur. Falsified.)
__global__ __launch_bounds__(256) void k_edge1(
    const unsigned* __restrict__ xlb, const float* __restrict__ xr,
    const int* __restrict__ rowptr, const unsigned* __restrict__ cpack,
    const float* __restrict__ We, const float* __restrict__ att,
    float* __restrict__ out1) {
    int lane = threadIdx.x & 63;
    int q = lane & 15, s = lane >> 4;
    int b = blockIdx.x;
    int wid = ((b & 7) << 10) + ((b >> 3) << 2) + (threadIdx.x >> 6);  // 0..8191
    int node = (int)(((long long)wid * NNODES) >> 13);
    int nend = (int)(((long long)(wid + 1) * NNODES) >> 13);
    if (node >= nend) return;
    const float C6 = 0.6f * L2E, C4 = 0.4f * L2E;
    float4 we0 = ((const float4*)We)[2 * q],  we1 = ((const float4*)We)[2 * q + 1];
    float4 av0 = ((const float4*)att)[2 * q], av1 = ((const float4*)att)[2 * q + 1];
    float4 aA0 = make_float4(av0.x * C6, av0.y * C6, av0.z * C6, av0.w * C6);
    float4 aB0 = make_float4(av0.x * C4, av0.y * C4, av0.z * C4, av0.w * C4);
    float4 aA1 = make_float4(av1.x * C6, av1.y * C6, av1.z * C6, av1.w * C6);
    float4 aB1 = make_float4(av1.x * C4, av1.y * C4, av1.z * C4, av1.w * C4);
    const uint4* xlv = (const uint4*)xlb;          // row = 16 uint4 (128 ch)
    int r0 = rowptr[node], r1 = rowptr[node + 1];
    float4 xr0 = ((const float4*)xr)[(size_t)node * 32 + 2 * q];
    float4 xr1 = ((const float4*)xr)[(size_t)node * 32 + 2 * q + 1];
    for (;;) {
        int nn = node + 1;
        bool more = nn < nend;
        int nr1 = 0;
        float4 nxr0 = make_float4(0.f, 0.f, 0.f, 0.f);
        float4 nxr1 = make_float4(0.f, 0.f, 0.f, 0.f);
        if (more) {                                // prefetch next node (contig)
            nr1 = rowptr[nn + 1];
            nxr0 = ((const float4*)xr)[(size_t)nn * 32 + 2 * q];
            nxr1 = ((const float4*)xr)[(size_t)nn * 32 + 2 * q + 1];
        }
        float den = 0.f;
        float a0 = 0.f, a1 = 0.f, a2 = 0.f, a3 = 0.f;
        float a4 = 0.f, a5 = 0.f, a6 = 0.f, a7 = 0.f;
        int nit = (r1 - r0 + 3) >> 2;
        int k = r0 + s;
        // sc ring: groups it..it+4 (all padded: safe)
        unsigned sc0 = cpack[k];
        unsigned sc1 = cpack[k + 4];
        unsigned sc2 = cpack[k + 8];
        unsigned sc3 = cpack[k + 12];
        unsigned sc4 = cpack[k + 16];
        // xv ring: gathers for groups it..it+2
        uint4 xv0 = xlv[(size_t)(sc0 & 0xffffu) * 16 + q];
        uint4 xv1 = xlv[(size_t)(sc1 & 0xffffu) * 16 + q];
        uint4 xv2 = xlv[(size_t)(sc2 & 0xffffu) * 16 + q];
        for (int it = 0; it < nit; it++) {
            unsigned scn = cpack[k + 20];                       // sc for group it+5
            uint4 xvn = xlv[(size_t)(sc3 & 0xffffu) * 16 + q];  // gather group it+3
            bool ok = k < r1;
            float av = __uint_as_float(sc0 & 0xffff0000u);  // bf16 attr
            float x0 = blo(xv0.x), x1 = bhi(xv0.x), x2 = blo(xv0.y), x3 = bhi(xv0.y);
            float x4 = blo(xv0.z), x5 = bhi(xv0.z), x6 = blo(xv0.w), x7 = bhi(xv0.w);
            float s0 = fmaf(av, we0.x, x0 + xr0.x);
            float s1 = fmaf(av, we0.y, x1 + xr0.y);
            float s2 = fmaf(av, we0.z, x2 + xr0.z);
            float s3 = fmaf(av, we0.w, x3 + xr0.w);
            float s4 = fmaf(av, we1.x, x4 + xr1.x);
            float s5 = fmaf(av, we1.y, x5 + xr1.y);
            float s6 = fmaf(av, we1.z, x6 + xr1.z);
            float s7 = fmaf(av, we1.w, x7 + xr1.w);
            float tA = s0 * aA0.x;            tA = fmaf(fabsf(s0), aB0.x, tA);
            tA = fmaf(s1, aA0.y, tA);         tA = fmaf(fabsf(s1), aB0.y, tA);
            tA = fmaf(s2, aA0.z, tA);         tA = fmaf(fabsf(s2), aB0.z, tA);
            tA = fmaf(s3, aA0.w, tA);         tA = fmaf(fabsf(s3), aB0.w, tA);
            float tB = s4 * aA1.x;            tB = fmaf(fabsf(s4), aB1.x, tB);
            tB = fmaf(s5, aA1.y, tB);         tB = fmaf(fabsf(s5), aB1.y, tB);
            tB = fmaf(s6, aA1.z, tB);         tB = fmaf(fabsf(s6), aB1.z, tB);
            tB = fmaf(s7, aA1.w, tB);         tB = fmaf(fabsf(s7), aB1.w, tB);
            float t = tA + tB;
            t += __shfl_xor(t, 1);
            t += __shfl_xor(t, 2);                 // 4-lane group = this lane's head
            float e = ok ? EXP2F(t) : 0.f;
            den += e;
            a0 = fmaf(e, x0, a0); a1 = fmaf(e, x1, a1);
            a2 = fmaf(e, x2, a2); a3 = fmaf(e, x3, a3);
            a4 = fmaf(e, x4, a4); a5 = fmaf(e, x5, a5);
            a6 = fmaf(e, x6, a6); a7 = fmaf(e, x7, a7);
            k += 4;
            sc0 = sc1; sc1 = sc2; sc2 = sc3; sc3 = sc4; sc4 = scn;
            xv0 = xv1; xv1 = xv2; xv2 = xvn;
        }
        // merge the 4 slots (lanes q, q+16, q+32, q+48 hold same channels/head)
        #pragma unroll
        for (int o = 16; o <= 32; o <<= 1) {
            den += __shfl_xor(den, o);
            a0 += __shfl_xor(a0, o); a1 += __shfl_xor(a1, o);
            a2 += __shfl_xor(a2, o); a3 += __shfl_xor(a3, o);
            a4 += __shfl_xor(a4, o); a5 += __shfl_xor(a5, o);
            a6 += __shfl_xor(a6, o); a7 += __shfl_xor(a7, o);
        }
        if (s == 0) {
            float rd = 1.f / den;
            ((float4*)out1)[(size_t)node * 32 + 2 * q] =
                make_float4(a0 * rd, a1 * rd, a2 * rd, a3 * rd);
            ((float4*)out1)[(size_t)node * 32 + 2 * q + 1] =
                make_float4(a4 * rd, a5 * rd, a6 * rd, a7 * rd);
        }
        if (!more) return;
        node = nn; r0 = r1; r1 = nr1; xr0 = nxr0; xr1 = nxr1;
    }
}

// ---------------- epi1 via MFMA: BN+ReLU staged, then h @ (Wl2|Wr2) ---------
__global__ __launch_bounds__(256) void k_epi(
    const float* __restrict__ out1, const float* __restrict__ bias1,
    const float* __restrict__ g1, const float* __restrict__ b1,
    const float* __restrict__ m1, const float* __restrict__ v1,
    const unsigned short* __restrict__ WT2,
    const float* __restrict__ bl2, const float* __restrict__ br2,
    unsigned* __restrict__ xlb2, float* __restrict__ xr2) {
    __shared__ short hs_s[64 * XSS];              // rows 0-31 hi, 32-63 lo
    __shared__ float A[128], B[128];
    int n0g = blockIdx.x * 32;
    if (threadIdx.x < 128) {
        int c = threadIdx.x;
        float sc = g1[c] * rsqrtf(v1[c] + BNEPS);
        A[c] = sc;
        B[c] = (bias1[c] - m1[c]) * sc + b1[c];
    }
    __syncthreads();
    {
        int nd = threadIdx.x >> 3, kc = (threadIdx.x & 7) * 16;
        bool valid = (n0g + nd) < NNODES;
        float xv[16];
        #pragma unroll
        for (int i = 0; i < 4; i++) {
            float4 t = valid ? ((const float4*)(out1 + (size_t)(n0g + nd) * C1 + kc))[i]
                             : make_float4(0.f, 0.f, 0.f, 0.f);
            xv[4 * i] = t.x; xv[4 * i + 1] = t.y; xv[4 * i + 2] = t.z; xv[4 * i + 3] = t.w;
        }
        #pragma unroll
        for (int j = 0; j < 16; j++)
            xv[j] = fmaxf(xv[j] * A[kc + j] + B[kc + j], 0.f);   // BN + ReLU
        unsigned hi[8], lo[8];
        #pragma unroll
        for (int i = 0; i < 8; i++) {
            unsigned short h0 = bf16r(xv[2 * i]), h1 = bf16r(xv[2 * i + 1]);
            float l0 = xv[2 * i]     - __uint_as_float(((unsigned)h0) << 16);
            float l1 = xv[2 * i + 1] - __uint_as_float(((unsigned)h1) << 16);
            hi[i] = (unsigned)h0 | ((unsigned)h1 << 16);
            lo[i] = bf16pair(l0, l1);
        }
        uint4* ph = (uint4*)&hs_s[nd * XSS + kc];
        ph[0] = make_uint4(hi[0], hi[1], hi[2], hi[3]);
        ph[1] = make_uint4(hi[4], hi[5], hi[6], hi[7]);
        uint4* pl = (uint4*)&hs_s[(nd + 32) * XSS + kc];
        pl[0] = make_uint4(lo[0], lo[1], lo[2], lo[3]);
        pl[1] = make_uint4(lo[4], lo[5], lo[6], lo[7]);
    }
    __syncthreads();
    int lane = threadIdx.x & 63;
    int lm = lane & 15, q = lane >> 4;
    int w = threadIdx.x >> 6;
    f32x4 acc[2];
    acc[0] = (f32x4)0.f; acc[1] = (f32x4)0.f;
    #pragma unroll
    for (int ks = 0; ks < 4; ks++) {
        int k0 = ks * 32 + q * 8;
        short8 ah0 = *(const short8*)&hs_s[(lm)      * XSS + k0];
        short8 ah1 = *(const short8*)&hs_s[(16 + lm) * XSS + k0];
        short8 al0 = *(const short8*)&hs_s[(32 + lm) * XSS + k0];
        short8 al1 = *(const short8*)&hs_s[(48 + lm) * XSS + k0];
        short8 bfr = *(const short8*)(WT2 + (size_t)(w * 16 + lm) * WTS + k0);
        acc[0] = __builtin_amdgcn_mfma_f32_16x16x32_bf16(al0, bfr, acc[0], 0, 0, 0);
        acc[0] = __builtin_amdgcn_mfma_f32_16x16x32_bf16(ah0, bfr, acc[0], 0, 0, 0);
        acc[1] = __builtin_amdgcn_mfma_f32_16x16x32_bf16(al1, bfr, acc[1], 0, 0, 0);
        acc[1] = __builtin_amdgcn_mfma_f32_16x16x32_bf16(ah1, bfr, acc[1], 0, 0, 0);
    }
    if (w < 2) {
        int ch = w * 16 + lm;                      // Wl2 col 0..31
        float bv = bl2[ch];
        #pragma unroll
        for (int mt = 0; mt < 2; mt++)
            #pragma unroll
            for (int r = 0; r < 4; r++) {
                int node = n0g + mt * 16 + q * 4 + r;
                float val = acc[mt][r] + bv;
                float pv = __shfl_xor(val, 1);
                if ((lm & 1) == 0 && node < NNODES)
                    xlb2[(size_t)node * 16 + (ch >> 1)] = bf16pair(val, pv);
            }
    } else {
        int ch = (w - 2) * 16 + lm;                // Wr2 col 0..31
        float bv = br2[ch];
        #pragma unroll
        for (int mt = 0; mt < 2; mt++)
            #pragma unroll
            for (int r = 0; r < 4; r++) {
                int node = n0g + mt * 16 + q * 4 + r;
                if (node < NNODES)
                    xr2[(size_t)node * HID + ch] = acc[mt][r] + bv;
            }
    }
}

// ---------------- conv2 fused edge phase + BN + classifier ------------------
// Same contiguous per-wave node ranges + XCD chunk swizzle as k_edge1.
__global__ __launch_bounds__(256) void k_edge2(
    const unsigned* __restrict__ xlb2, const float* __restrict__ xr2,
    const int* __restrict__ rowptr, const unsigned* __restrict__ cpack,
    const float* __restrict__ We2, const float* __restrict__ att2,
    const float* __restrict__ bias2,
    const float* __restrict__ g2, const float* __restrict__ b2,
    const float* __restrict__ m2, const float* __restrict__ v2,
    const float* __restrict__ W, const float* __restrict__ b,
    float* __restrict__ y) {
    int lane = threadIdx.x & 63;
    int q = lane & 7, s = lane >> 3;
    int bb = blockIdx.x;
    int wid = ((bb & 7) << 10) + ((bb >> 3) << 2) + (threadIdx.x >> 6);  // 0..8191
    int node = (int)(((long long)wid * NNODES) >> 13);
    int nend = (int)(((long long)(wid + 1) * NNODES) >> 13);
    if (node >= nend) return;
    const float C6 = 0.6f * L2E, C4 = 0.4f * L2E;
    float4 we = ((const float4*)We2)[q];
    float4 av4 = ((const float4*)att2)[q];
    float4 aA = make_float4(av4.x * C6, av4.y * C6, av4.z * C6, av4.w * C6);
    float4 aB = make_float4(av4.x * C4, av4.y * C4, av4.z * C4, av4.w * C4);
    // fold BN: h = (a*rd + bias - m)*sc + bb = (a*rd)*sA + sB
    float4 gv = ((const float4*)g2)[q];
    float4 bv = ((const float4*)b2)[q];
    float4 mv = ((const float4*)m2)[q];
    float4 vv = ((const float4*)v2)[q];
    float4 bi = ((const float4*)bias2)[q];
    float4 sA, sB;
    sA.x = gv.x * rsqrtf(vv.x + BNEPS); sB.x = (bi.x - mv.x) * sA.x + bv.x;
    sA.y = gv.y * rsqrtf(vv.y + BNEPS); sB.y = (bi.y - mv.y) * sA.y + bv.y;
    sA.z = gv.z * rsqrtf(vv.z + BNEPS); sB.z = (bi.z - mv.z) * sA.z + bv.z;
    sA.w = gv.w * rsqrtf(vv.w + BNEPS); sB.w = (bi.w - mv.w) * sA.w + bv.w;
    float4 w0 = ((const float4*)W)[2 * q];         // ch 4q,4q+1 x {out0,out1}
    float4 w1 = ((const float4*)W)[2 * q + 1];     // ch 4q+2,4q+3
    float bb0 = b[0], bb1 = b[1];
    const uint2* xlv = (const uint2*)xlb2;         // row = 8 uint2 (32 ch)
    int r0 = rowptr[node], r1 = rowptr[node + 1];
    float4 xr0 = ((const float4*)xr2)[(size_t)node * 8 + q];
    for (;;) {
        int nn = node + 1;
        bool more = nn < nend;
        int nr1 = 0;
        float4 nxr0 = make_float4(0.f, 0.f, 0.f, 0.f);
        if (more) {                                // prefetch next node (contig)
            nr1 = rowptr[nn + 1];
            nxr0 = ((const float4*)xr2)[(size_t)nn * 8 + q];
        }
        float den = 0.f;
        float a0 = 0.f, a1 = 0.f, a2 = 0.f, a3 = 0.f;
        int nit = (r1 - r0 + 7) >> 3;
        int k = r0 + s;
        unsigned sc0 = cpack[k];
        unsigned sc1 = cpack[k + 8];
        unsigned sc2 = cpack[k + 16];
        unsigned sc3 = cpack[k + 24];
        unsigned sc4 = cpack[k + 32];
        uint2 xv0 = xlv[(size_t)(sc0 & 0xffffu) * 8 + q];
        uint2 xv1 = xlv[(size_t)(sc1 & 0xffffu) * 8 + q];
        uint2 xv2 = xlv[(size_t)(sc2 & 0xffffu) * 8 + q];
        for (int it = 0; it < nit; it++) {
            unsigned scn = cpack[k + 40];                      // sc for group it+5
            uint2 xvn = xlv[(size_t)(sc3 & 0xffffu) * 8 + q];  // gather group it+3
            bool ok = k < r1;
            float av = __uint_as_float(sc0 & 0xffff0000u);
            float x0 = blo(xv0.x), x1 = bhi(xv0.x), x2 = blo(xv0.y), x3 = bhi(xv0.y);
            float s0 = fmaf(av, we.x, x0 + xr0.x);
            float s1 = fmaf(av, we.y, x1 + xr0.y);
            float s2 = fmaf(av, we.z, x2 + xr0.z);
            float s3 = fmaf(av, we.w, x3 + xr0.w);
            float tA = s0 * aA.x;             tA = fmaf(fabsf(s0), aB.x, tA);
            tA = fmaf(s1, aA.y, tA);          tA = fmaf(fabsf(s1), aB.y, tA);
            float tB = s2 * aA.z;             tB = fmaf(fabsf(s2), aB.z, tB);
            tB = fmaf(s3, aA.w, tB);          tB = fmaf(fabsf(s3), aB.w, tB);
            float t = tA + tB;
            t += __shfl_xor(t, 1);
            t += __shfl_xor(t, 2);
            t += __shfl_xor(t, 4);                 // 8-lane group = full logit
            float e = ok ? EXP2F(t) : 0.f;
            den += e;
            a0 = fmaf(e, x0, a0); a1 = fmaf(e, x1, a1);
            a2 = fmaf(e, x2, a2); a3 = fmaf(e, x3, a3);
            k += 8;
            sc0 = sc1; sc1 = sc2; sc2 = sc3; sc3 = sc4; sc4 = scn;
            xv0 = xv1; xv1 = xv2; xv2 = xvn;
        }
        #pragma unroll
        for (int o = 8; o <= 32; o <<= 1) {        // merge 8 slots
            den += __shfl_xor(den, o);
            a0 += __shfl_xor(a0, o); a1 += __shfl_xor(a1, o);
            a2 += __shfl_xor(a2, o); a3 += __shfl_xor(a3, o);
        }
        float rd = 1.f / den;
        float h0 = fmaxf(fmaf(a0 * rd, sA.x, sB.x), 0.f);
        float h1 = fmaxf(fmaf(a1 * rd, sA.y, sB.y), 0.f);
        float h2 = fmaxf(fmaf(a2 * rd, sA.z, sB.z), 0.f);
        float h3 = fmaxf(fmaf(a3 * rd, sA.w, sB.w), 0.f);
        float u0 = h0 * w0.x + h1 * w0.z + h2 * w1.x + h3 * w1.z;
        float u1 = h0 * w0.y + h1 * w0.w + h2 * w1.y + h3 * w1.w;
        u0 += __shfl_xor(u0, 1); u0 += __shfl_xor(u0, 2); u0 += __shfl_xor(u0, 4);
        u1 += __shfl_xor(u1, 1); u1 += __shfl_xor(u1, 2); u1 += __shfl_xor(u1, 4);
        if (lane == 0) {
            y[(size_t)node * 2]     = u0 + bb0;
            y[(size_t)node * 2 + 1] = u1 + bb1;
        }
        if (!more) return;
        node = nn; r0 = r1; r1 = nr1; xr0 = nxr0;
    }
}

extern "C" void kernel_launch(void* const* d_in, const int* in_sizes, int n_in,
                              void* d_out, int out_size, void* d_ws, size_t ws_size,
                              hipStream_t stream) {
    const float* x       = (const float*)d_in[0];
    const int*   ei      = (const int*)d_in[1];
    const float* ea      = (const float*)d_in[2];
    const float* c1_Wl   = (const float*)d_in[3];
    const float* c1_bl   = (const float*)d_in[4];
    const float* c1_Wr   = (const float*)d_in[5];
    const float* c1_br   = (const float*)d_in[6];
    const float* c1_We   = (const float*)d_in[7];
    const float* c1_att  = (const float*)d_in[8];
    const float* c1_bias = (const float*)d_in[9];
    const float* bn1_g   = (const float*)d_in[10];
    const float* bn1_b   = (const float*)d_in[11];
    const float* bn1_m   = (const float*)d_in[12];
    const float* bn1_v   = (const float*)d_in[13];
    const float* c2_Wl   = (const float*)d_in[14];
    const float* c2_bl   = (const float*)d_in[15];
    const float* c2_Wr   = (const float*)d_in[16];
    const float* c2_br   = (const float*)d_in[17];
    const float* c2_We   = (const float*)d_in[18];
    const float* c2_att  = (const float*)d_in[19];
    const float* c2_bias = (const float*)d_in[20];
    const float* bn2_g   = (const float*)d_in[21];
    const float* bn2_b   = (const float*)d_in[22];
    const float* bn2_m   = (const float*)d_in[23];
    const float* bn2_v   = (const float*)d_in[24];
    const float* clf_W   = (const float*)d_in[25];
    const float* clf_b   = (const float*)d_in[26];

    float* ws = (float*)d_ws;
    size_t off = 0;
    unsigned* XLb  = (unsigned*)(ws + off); off += (size_t)NNODES * 64;  // bf16x2
    float*    XR1  = ws + off; off += (size_t)NNODES * C1;
    float*    OUT1 = ws + off; off += (size_t)NNODES * C1;
    unsigned* XLb2 = (unsigned*)(ws + off); off += (size_t)NNODES * 16;  // bf16x2
    float*    XR2  = ws + off; off += (size_t)NNODES * HID;
    unsigned* CPACK= (unsigned*)(ws + off); off += (size_t)ETOT + 64;    // 4B/edge
    unsigned short* WT  = (unsigned short*)(ws + off); off += 256 * WTS / 2;
    unsigned short* WT2 = (unsigned short*)(ws + off); off += 64 * WTS / 2;
    int*      EOFF = (int*)(ws + off); off += NEDGES;
    int*      ROWP = (int*)(ws + off); off += NNODES + 16;
    int*      DEG  = (int*)(ws + off); off += NNODES;
    int*      BSUM = (int*)(ws + off); off += 256;
    int*      HIST = (int*)(ws + off); off += (size_t)NC * NNODES;  // zeroed by k_prep
    float*    MEANB= ws + off; off += 64;
    if (ws_size < off * sizeof(float)) return;  // workspace too small: fail loudly

    k_prep  <<<160, 256, 0, stream>>>(c1_Wl, c1_Wr, c2_Wl, c2_Wr, WT, WT2, HIST, MEANB);
    k_xf_eh <<<XFEB, 256, 0, stream>>>(x, c1_bl, c1_br, WT, XLb, XR1,
                                       ei, ea, HIST, EOFF, MEANB);
    k_red   <<<SCB, 256, 0, stream>>>(HIST, DEG, BSUM);
    k_rowp  <<<SCB, 256, 0, stream>>>(DEG, BSUM, ROWP);
    k_fill  <<<FEB + FLB + 1, 256, 0, stream>>>(ei, ea, ROWP, MEANB, HIST, EOFF, CPACK);
    k_edge1 <<<EB1, 256, 0, stream>>>(XLb, XR1, ROWP, CPACK, c1_We, c1_att, OUT1);
    k_epi   <<<XFB2, 256, 0, stream>>>(OUT1, c1_bias, bn1_g, bn1_b, bn1_m, bn1_v,
                                       WT2, c2_bl, c2_br, XLb2, XR2);
    k_edge2 <<<EB2, 256, 0, stream>>>(XLb2, XR2, ROWP, CPACK, c2_We, c2_att,
                                      c2_bias, bn2_g, bn2_b, bn2_m, bn2_v,
                                      clf_W, clf_b, (float*)d_out);
}

// Round 7
// 292.351 us; speedup vs baseline: 1.1757x; 1.0000x over previous
//
#include <hip/hip_runtime.h>

#define NNODES 50000
#define NEDGES 800000
#define ETOT   850000   /* NEDGES + NNODES self loops */
#define IN_CH  128
#define HID    32
#define C1     128      /* HEADS*HID */
#define NEG    0.2f
#define BNEPS  1e-5f
#define XFB2   1563     /* gemm blocks = ceil(NNODES/32) */
#define HB8    391      /* hist blocks, 2048 edges each = ceil(NEDGES/2048) */
#define XFEB   1955     /* k_xf_eh grid = 5*HB8 (1:4 hist:gemm interleave) */
#define WTS    160      /* WT row stride in bf16 (320B) */
#define XSS    136      /* xs LDS row stride in bf16 */
#define NC     16       /* histogram replication factor */
#define SCB    196      /* scan blocks = ceil(NNODES/256) */
#define FEB    782      /* k_fill edge blocks (1024 edges each) */
#define FLB    49       /* k_fill self-loop blocks (1024 nodes each) */
#define EB1    2048     /* k_edge1 persistent blocks */
#define EB2    2048     /* k_edge2 persistent blocks */
#define L2E    1.4426950408889634f

#if defined(__has_builtin)
#if __has_builtin(__builtin_amdgcn_exp2f)
#define EXP2F(x) __builtin_amdgcn_exp2f(x)
#endif
#endif
#ifndef EXP2F
#define EXP2F(x) exp2f(x)
#endif

typedef __attribute__((ext_vector_type(8))) short short8;
typedef __attribute__((ext_vector_type(4))) float f32x4;

// fp32 -> bf16 (RNE)
__device__ __forceinline__ unsigned short bf16r(float f) {
    unsigned u = __float_as_uint(f);
    return (unsigned short)((u + 0x7fffu + ((u >> 16) & 1u)) >> 16);
}
__device__ __forceinline__ unsigned bf16pair(float f0, float f1) {
    return (unsigned)bf16r(f0) | ((unsigned)bf16r(f1) << 16);
}
__device__ __forceinline__ float blo(unsigned u) { return __uint_as_float(u << 16); }
__device__ __forceinline__ float bhi(unsigned u) { return __uint_as_float(u & 0xffff0000u); }

// 256-thread block inclusive scan (4 waves, shfl_up + LDS wave offsets)
__device__ __forceinline__ int block_iscan(int v, int* ls) {
    int lane = threadIdx.x & 63, w = threadIdx.x >> 6;
    #pragma unroll
    for (int o = 1; o < 64; o <<= 1) {
        int t = __shfl_up(v, o);
        if (lane >= o) v += t;
    }
    if (lane == 63) ls[w] = v;
    __syncthreads();
    int add = 0;
    #pragma unroll
    for (int i = 0; i < 4; i++) add += (i < w) ? ls[i] : 0;
    return v + add;
}

// ---------------- prep: bf16-transposed weights + zero HIST/MEANB -----------
__global__ __launch_bounds__(256) void k_prep(const float* __restrict__ Wl1,
                                              const float* __restrict__ Wr1,
                                              const float* __restrict__ Wl2,
                                              const float* __restrict__ Wr2,
                                              unsigned short* __restrict__ WT,
                                              unsigned short* __restrict__ WT2,
                                              int* __restrict__ hist,
                                              float* __restrict__ meanbuf) {
    int idx = blockIdx.x * 256 + threadIdx.x;     // 160 blocks -> 40960
    if (idx == 0) meanbuf[0] = 0.f;
    for (int i = idx; i < NC * NNODES; i += 160 * 256) hist[i] = 0;  // coalesced zero
    if (idx < 32768) {
        int mat = idx >> 14, rem = idx & 16383;
        int k = rem >> 7, n = rem & 127;
        float v = mat ? Wr1[k * 128 + n] : Wl1[k * 128 + n];
        WT[(size_t)(mat * 128 + n) * WTS + k] = bf16r(v);
    } else {
        int i2 = idx - 32768;                      // 8192 elements
        int mat = i2 >> 12, rem = i2 & 4095;
        int k = rem >> 5, n = rem & 31;
        float v = mat ? Wr2[k * 32 + n] : Wl2[k * 32 + n];
        WT2[(size_t)(mat * 32 + n) * WTS + k] = bf16r(v);
    }
}

// ---------------- fused & INTERLEAVED: conv1 MFMA GEMM + histogram ----------
// xr is now stored as bf16 pairs (xrb) -- halves the write here and the
// per-node read in k_edge1. xr only feeds attention logits (never the
// output accumulation), so bf16 rounding is benign.
__global__ __launch_bounds__(256) void k_xf_eh(
    const float* __restrict__ x,
    const float* __restrict__ bl, const float* __restrict__ br,
    const unsigned short* __restrict__ WT,
    unsigned* __restrict__ xlb, unsigned* __restrict__ xrb,
    const int* __restrict__ ei, const float* __restrict__ ea,
    int* __restrict__ hist, int* __restrict__ eoff,
    float* __restrict__ meanbuf) {
    __shared__ short xs_s[64 * XSS];              // rows 0-31 hi, 32-63 lo
    int bi = blockIdx.x;
    if (bi % 5 == 0) {
        // ---- histogram (replicated) + edge_attr mean + slot offset ----
        float* ls = (float*)xs_s;
        int hb = bi / 5;                           // 0..390
        int e0 = hb * 2048 + threadIdx.x;
        float v = 0.f;
        if (hb < HB8 - 1) {                        // full block: no bounds checks
            #pragma unroll
            for (int j = 0; j < 8; j++) {
                int e = e0 + 256 * j;
                int c = (8 * hb + j) & (NC - 1);   // = (e>>8)&15, matches k_fill
                eoff[e] = atomicAdd(&hist[c * NNODES + ei[NEDGES + e]], 1);
                v += ea[e];
            }
        } else {
            #pragma unroll
            for (int j = 0; j < 8; j++) {
                int e = e0 + 256 * j;
                if (e < NEDGES) {
                    int c = (8 * hb + j) & (NC - 1);
                    eoff[e] = atomicAdd(&hist[c * NNODES + ei[NEDGES + e]], 1);
                    v += ea[e];
                }
            }
        }
        #pragma unroll
        for (int o = 32; o > 0; o >>= 1) v += __shfl_down(v, o, 64);
        if ((threadIdx.x & 63) == 0) ls[threadIdx.x >> 6] = v;
        __syncthreads();
        if (threadIdx.x == 0) atomicAdd(meanbuf, ls[0] + ls[1] + ls[2] + ls[3]);
        return;
    }
    int g = bi - bi / 5 - 1;                       // GEMM ordinal
    if (g >= XFB2) return;
    int n0g = g * 32;
    // ---- stage x tile: 32 nodes x 128 k, bf16 hi + lo ----
    {
        int nd = threadIdx.x >> 3, kc = (threadIdx.x & 7) * 16;
        bool valid = (n0g + nd) < NNODES;
        float xv[16];
        #pragma unroll
        for (int i = 0; i < 4; i++) {
            float4 t = valid ? ((const float4*)(x + (size_t)(n0g + nd) * IN_CH + kc))[i]
                             : make_float4(0.f, 0.f, 0.f, 0.f);
            xv[4 * i] = t.x; xv[4 * i + 1] = t.y; xv[4 * i + 2] = t.z; xv[4 * i + 3] = t.w;
        }
        unsigned hi[8], lo[8];
        #pragma unroll
        for (int i = 0; i < 8; i++) {
            unsigned short h0 = bf16r(xv[2 * i]), h1 = bf16r(xv[2 * i + 1]);
            float l0 = xv[2 * i]     - __uint_as_float(((unsigned)h0) << 16);
            float l1 = xv[2 * i + 1] - __uint_as_float(((unsigned)h1) << 16);
            hi[i] = (unsigned)h0 | ((unsigned)h1 << 16);
            lo[i] = bf16pair(l0, l1);
        }
        uint4* ph = (uint4*)&xs_s[nd * XSS + kc];
        ph[0] = make_uint4(hi[0], hi[1], hi[2], hi[3]);
        ph[1] = make_uint4(hi[4], hi[5], hi[6], hi[7]);
        uint4* pl = (uint4*)&xs_s[(nd + 32) * XSS + kc];
        pl[0] = make_uint4(lo[0], lo[1], lo[2], lo[3]);
        pl[1] = make_uint4(lo[4], lo[5], lo[6], lo[7]);
    }
    __syncthreads();
    int lane = threadIdx.x & 63;
    int lm = lane & 15, q = lane >> 4;
    int w = threadIdx.x >> 6;
    int n0 = w * 64;                               // this wave's 64 output cols
    f32x4 acc[2][4];
    #pragma unroll
    for (int mt = 0; mt < 2; mt++)
        #pragma unroll
        for (int nt = 0; nt < 4; nt++) acc[mt][nt] = (f32x4)0.f;

    #pragma unroll
    for (int ks = 0; ks < 4; ks++) {
        int k0 = ks * 32 + q * 8;
        short8 ah0 = *(const short8*)&xs_s[(lm)      * XSS + k0];
        short8 ah1 = *(const short8*)&xs_s[(16 + lm) * XSS + k0];
        short8 al0 = *(const short8*)&xs_s[(32 + lm) * XSS + k0];
        short8 al1 = *(const short8*)&xs_s[(48 + lm) * XSS + k0];
        #pragma unroll
        for (int nt = 0; nt < 4; nt++) {
            short8 bfr = *(const short8*)(WT + (size_t)(n0 + nt * 16 + lm) * WTS + k0);
            acc[0][nt] = __builtin_amdgcn_mfma_f32_16x16x32_bf16(al0, bfr, acc[0][nt], 0, 0, 0);
            acc[0][nt] = __builtin_amdgcn_mfma_f32_16x16x32_bf16(ah0, bfr, acc[0][nt], 0, 0, 0);
            acc[1][nt] = __builtin_amdgcn_mfma_f32_16x16x32_bf16(al1, bfr, acc[1][nt], 0, 0, 0);
            acc[1][nt] = __builtin_amdgcn_mfma_f32_16x16x32_bf16(ah1, bfr, acc[1][nt], 0, 0, 0);
        }
    }
    // ---- epilogue: D row=(q*4+reg), col=lm ----
    if (w < 2) {
        #pragma unroll
        for (int nt = 0; nt < 4; nt++) {
            int ch = n0 + nt * 16 + lm;
            float bv = bl[ch];
            #pragma unroll
            for (int mt = 0; mt < 2; mt++)
                #pragma unroll
                for (int r = 0; r < 4; r++) {
                    int node = n0g + mt * 16 + q * 4 + r;
                    float val = acc[mt][nt][r] + bv;
                    float pv = __shfl_xor(val, 1);
                    if ((lm & 1) == 0 && node < NNODES)
                        xlb[(size_t)node * 64 + (ch >> 1)] = bf16pair(val, pv);
                }
        }
    } else {
        #pragma unroll
        for (int nt = 0; nt < 4; nt++) {
            int ch = n0 - 128 + nt * 16 + lm;
            float bv = br[ch];
            #pragma unroll
            for (int mt = 0; mt < 2; mt++)
                #pragma unroll
                for (int r = 0; r < 4; r++) {
                    int node = n0g + mt * 16 + q * 4 + r;
                    float val = acc[mt][nt][r] + bv;
                    float pv = __shfl_xor(val, 1);
                    if ((lm & 1) == 0 && node < NNODES)
                        xrb[(size_t)node * 64 + (ch >> 1)] = bf16pair(val, pv);
                }
        }
    }
}

// ---------------- reduce 16 histogram copies -> DEG + per-block sums --------
__global__ __launch_bounds__(256) void k_red(int* __restrict__ hist,
                                             int* __restrict__ deg,
                                             int* __restrict__ bsum) {
    __shared__ int ls[4];
    int d = blockIdx.x * 256 + threadIdx.x;
    int s = 0;
    if (d < NNODES) {
        #pragma unroll
        for (int c = 0; c < NC; c++) {
            int v = hist[c * NNODES + d];
            hist[c * NNODES + d] = s;
            s += v;
        }
        deg[d] = s;
    }
    int v = (d < NNODES) ? s + 1 : 0;              // +1 = self loop
    #pragma unroll
    for (int o = 32; o > 0; o >>= 1) v += __shfl_down(v, o, 64);
    if ((threadIdx.x & 63) == 0) ls[threadIdx.x >> 6] = v;
    __syncthreads();
    if (threadIdx.x == 0) bsum[blockIdx.x] = ls[0] + ls[1] + ls[2] + ls[3];
}

// ---------------- rowptr: inline bsum scan + in-block exclusive scan --------
__global__ __launch_bounds__(256) void k_rowp(const int* __restrict__ deg,
                                              const int* __restrict__ bsum,
                                              int* __restrict__ rowptr) {
    __shared__ int ls[4];
    int t = threadIdx.x;
    int bv = (t < SCB) ? bsum[t] : 0;
    int bincl = block_iscan(bv, ls);
    __shared__ int boffs[256];
    boffs[t] = bincl - bv;
    __syncthreads();
    int base = boffs[blockIdx.x];
    __syncthreads();                               // ls reuse barrier
    int d = blockIdx.x * 256 + t;
    int v = (d < NNODES) ? deg[d] + 1 : 0;
    int incl = block_iscan(v, ls);
    if (d < NNODES) rowptr[d] = base + incl - v;
    if (d == NNODES - 1) rowptr[NNODES] = base + incl;
}

// ---------------- CSR fill: ATOMIC-FREE, 4 elements/thread ------------------
__global__ __launch_bounds__(256) void k_fill(const int* __restrict__ ei,
                                              const float* __restrict__ ea,
                                              const int* __restrict__ rowptr,
                                              const float* __restrict__ meanbuf,
                                              const int* __restrict__ hist,
                                              const int* __restrict__ eoff,
                                              unsigned* __restrict__ cpack) {
    int blk = blockIdx.x, tid = threadIdx.x;
    if (blk < FEB) {
        int e0 = blk * 1024 + tid;
        int d[4], sv[4], rp[4], hs[4], eo[4];
        float av[4];
        bool ok[4];
        #pragma unroll
        for (int j = 0; j < 4; j++) {
            int e = e0 + 256 * j;
            ok[j] = e < NEDGES;
            int es = ok[j] ? e : 0;
            d[j]  = ei[NEDGES + es];
            sv[j] = ei[es];
            av[j] = ea[es];
            eo[j] = eoff[es];
        }
        #pragma unroll
        for (int j = 0; j < 4; j++) {
            int e = e0 + 256 * j;
            int c = (e >> 8) & (NC - 1);
            rp[j] = rowptr[d[j]];
            hs[j] = hist[c * NNODES + d[j]];
        }
        #pragma unroll
        for (int j = 0; j < 4; j++)
            if (ok[j])
                cpack[rp[j] + 1 + hs[j] + eo[j]] =
                    ((unsigned)bf16r(av[j]) << 16) | (unsigned)sv[j];
        return;
    }
    if (blk < FEB + FLB) {
        float mv = meanbuf[0] * (1.0f / NEDGES);
        unsigned mp = ((unsigned)bf16r(mv)) << 16;
        int i0 = (blk - FEB) * 1024 + tid;
        int rp[4];
        bool ok[4];
        #pragma unroll
        for (int j = 0; j < 4; j++) {
            int i = i0 + 256 * j;
            ok[j] = i < NNODES;
            rp[j] = rowptr[ok[j] ? i : 0];
        }
        #pragma unroll
        for (int j = 0; j < 4; j++)
            if (ok[j]) cpack[rp[j]] = mp | (unsigned)(i0 + 256 * j);
        return;
    }
    if (tid < 64) cpack[ETOT + tid] = 0u;          // pad for prefetch overrun
}

// ---------------- conv1 fused edge phase: persistent waves (strided) --------
// r3-proven strided mapping (node = blk*4+w, stride 8192) + decoupled sc
// ring (5) / xv ring (3). xr read as bf16 pairs (uint4/node/lane); out1
// written as bf16 pairs -- halves this kernel's write traffic. Lean
// ~48-VGPR body (r5 matvec fusion falsified: +76 VGPR -> half occ -> 2x).
__global__ __launch_bounds__(256) void k_edge1(
    const unsigned* __restrict__ xlb, const unsigned* __restrict__ xrb,
    const int* __restrict__ rowptr, const unsigned* __restrict__ cpack,
    const float* __restrict__ We, const float* __restrict__ att,
    unsigned* __restrict__ out1b) {
    int lane = threadIdx.x & 63;
    int q = lane & 15, s = lane >> 4;
    int node = blockIdx.x * 4 + (threadIdx.x >> 6);
    if (node >= NNODES) return;
    const int W = EB1 * 4;
    const float C6 = 0.6f * L2E, C4 = 0.4f * L2E;
    float4 we0 = ((const float4*)We)[2 * q],  we1 = ((const float4*)We)[2 * q + 1];
    float4 av0 = ((const float4*)att)[2 * q], av1 = ((const float4*)att)[2 * q + 1];
    float4 aA0 = make_float4(av0.x * C6, av0.y * C6, av0.z * C6, av0.w * C6);
    float4 aB0 = make_float4(av0.x * C4, av0.y * C4, av0.z * C4, av0.w * C4);
    float4 aA1 = make_float4(av1.x * C6, av1.y * C6, av1.z * C6, av1.w * C6);
    float4 aB1 = make_float4(av1.x * C4, av1.y * C4, av1.z * C4, av1.w * C4);
    const uint4* xlv = (const uint4*)xlb;          // row = 16 uint4 (128 ch)
    const uint4* xrv = (const uint4*)xrb;          // row = 16 uint4 (128 ch)
    int r0 = rowptr[node], r1 = rowptr[node + 1];
    uint4 xu = xrv[(size_t)node * 16 + q];         // this lane's 8 xr channels
    for (;;) {
        int nn = node + W;
        bool more = nn < NNODES;
        int nr0 = 0, nr1 = 0;
        uint4 nxu = make_uint4(0u, 0u, 0u, 0u);
        if (more) {                                // prefetch next node
            nr0 = rowptr[nn]; nr1 = rowptr[nn + 1];
            nxu = xrv[(size_t)nn * 16 + q];
        }
        float y0 = blo(xu.x), y1 = bhi(xu.x), y2 = blo(xu.y), y3 = bhi(xu.y);
        float y4 = blo(xu.z), y5 = bhi(xu.z), y6 = blo(xu.w), y7 = bhi(xu.w);
        float den = 0.f;
        float a0 = 0.f, a1 = 0.f, a2 = 0.f, a3 = 0.f;
        float a4 = 0.f, a5 = 0.f, a6 = 0.f, a7 = 0.f;
        int nit = (r1 - r0 + 3) >> 2;
        int k = r0 + s;
        // sc ring: groups it..it+4 (all padded: safe)
        unsigned sc0 = cpack[k];
        unsigned sc1 = cpack[k + 4];
        unsigned sc2 = cpack[k + 8];
        unsigned sc3 = cpack[k + 12];
        unsigned sc4 = cpack[k + 16];
        // xv ring: gathers for groups it..it+2
        uint4 xv0 = xlv[(size_t)(sc0 & 0xffffu) * 16 + q];
        uint4 xv1 = xlv[(size_t)(sc1 & 0xffffu) * 16 + q];
        uint4 xv2 = xlv[(size_t)(sc2 & 0xffffu) * 16 + q];
        for (int it = 0; it < nit; it++) {
            unsigned scn = cpack[k + 20];                       // sc for group it+5
            uint4 xvn = xlv[(size_t)(sc3 & 0xffffu) * 16 + q];  // gather group it+3
            bool ok = k < r1;
            float av = __uint_as_float(sc0 & 0xffff0000u);  // bf16 attr
            float x0 = blo(xv0.x), x1 = bhi(xv0.x), x2 = blo(xv0.y), x3 = bhi(xv0.y);
            float x4 = blo(xv0.z), x5 = bhi(xv0.z), x6 = blo(xv0.w), x7 = bhi(xv0.w);
            float s0 = fmaf(av, we0.x, x0 + y0);
            float s1 = fmaf(av, we0.y, x1 + y1);
            float s2 = fmaf(av, we0.z, x2 + y2);
            float s3 = fmaf(av, we0.w, x3 + y3);
            float s4 = fmaf(av, we1.x, x4 + y4);
            float s5 = fmaf(av, we1.y, x5 + y5);
            float s6 = fmaf(av, we1.z, x6 + y6);
            float s7 = fmaf(av, we1.w, x7 + y7);
            float tA = s0 * aA0.x;            tA = fmaf(fabsf(s0), aB0.x, tA);
            tA = fmaf(s1, aA0.y, tA);         tA = fmaf(fabsf(s1), aB0.y, tA);
            tA = fmaf(s2, aA0.z, tA);         tA = fmaf(fabsf(s2), aB0.z, tA);
            tA = fmaf(s3, aA0.w, tA);         tA = fmaf(fabsf(s3), aB0.w, tA);
            float tB = s4 * aA1.x;            tB = fmaf(fabsf(s4), aB1.x, tB);
            tB = fmaf(s5, aA1.y, tB);         tB = fmaf(fabsf(s5), aB1.y, tB);
            tB = fmaf(s6, aA1.z, tB);         tB = fmaf(fabsf(s6), aB1.z, tB);
            tB = fmaf(s7, aA1.w, tB);         tB = fmaf(fabsf(s7), aB1.w, tB);
            float t = tA + tB;
            t += __shfl_xor(t, 1);
            t += __shfl_xor(t, 2);                 // 4-lane group = this lane's head
            float e = ok ? EXP2F(t) : 0.f;
            den += e;
            a0 = fmaf(e, x0, a0); a1 = fmaf(e, x1, a1);
            a2 = fmaf(e, x2, a2); a3 = fmaf(e, x3, a3);
            a4 = fmaf(e, x4, a4); a5 = fmaf(e, x5, a5);
            a6 = fmaf(e, x6, a6); a7 = fmaf(e, x7, a7);
            k += 4;
            sc0 = sc1; sc1 = sc2; sc2 = sc3; sc3 = sc4; sc4 = scn;
            xv0 = xv1; xv1 = xv2; xv2 = xvn;
        }
        // merge the 4 slots (lanes q, q+16, q+32, q+48 hold same channels/head)
        #pragma unroll
        for (int o = 16; o <= 32; o <<= 1) {
            den += __shfl_xor(den, o);
            a0 += __shfl_xor(a0, o); a1 += __shfl_xor(a1, o);
            a2 += __shfl_xor(a2, o); a3 += __shfl_xor(a3, o);
            a4 += __shfl_xor(a4, o); a5 += __shfl_xor(a5, o);
            a6 += __shfl_xor(a6, o); a7 += __shfl_xor(a7, o);
        }
        if (s == 0) {                              // out1 as bf16 pairs (16B/lane)
            float rd = 1.f / den;
            uint4 o;
            o.x = bf16pair(a0 * rd, a1 * rd);
            o.y = bf16pair(a2 * rd, a3 * rd);
            o.z = bf16pair(a4 * rd, a5 * rd);
            o.w = bf16pair(a6 * rd, a7 * rd);
            ((uint4*)out1b)[(size_t)node * 16 + q] = o;
        }
        if (!more) return;
        node = nn; r0 = nr0; r1 = nr1; xu = nxu;
    }
}

// ---------------- epi1 via MFMA: BN+ReLU staged, then h @ (Wl2|Wr2) ---------
// out1 is bf16 pairs now: half the read traffic; BN output stays f32 and
// the hi/lo split below preserves its precision into the MFMA.
__global__ __launch_bounds__(256) void k_epi(
    const unsigned* __restrict__ out1b, const float* __restrict__ bias1,
    const float* __restrict__ g1, const float* __restrict__ b1,
    const float* __restrict__ m1, const float* __restrict__ v1,
    const unsigned short* __restrict__ WT2,
    const float* __restrict__ bl2, const float* __restrict__ br2,
    unsigned* __restrict__ xlb2, float* __restrict__ xr2) {
    __shared__ short hs_s[64 * XSS];              // rows 0-31 hi, 32-63 lo
    __shared__ float A[128], B[128];
    int n0g = blockIdx.x * 32;
    if (threadIdx.x < 128) {
        int c = threadIdx.x;
        float sc = g1[c] * rsqrtf(v1[c] + BNEPS);
        A[c] = sc;
        B[c] = (bias1[c] - m1[c]) * sc + b1[c];
    }
    __syncthreads();
    {
        int nd = threadIdx.x >> 3, kc = (threadIdx.x & 7) * 16;
        bool valid = (n0g + nd) < NNODES;
        uint4 z = make_uint4(0u, 0u, 0u, 0u);
        uint4 u0 = valid ? ((const uint4*)out1b)[(size_t)(n0g + nd) * 16 + (threadIdx.x & 7) * 2]     : z;
        uint4 u1 = valid ? ((const uint4*)out1b)[(size_t)(n0g + nd) * 16 + (threadIdx.x & 7) * 2 + 1] : z;
        float xv[16];
        xv[0]  = blo(u0.x); xv[1]  = bhi(u0.x); xv[2]  = blo(u0.y); xv[3]  = bhi(u0.y);
        xv[4]  = blo(u0.z); xv[5]  = bhi(u0.z); xv[6]  = blo(u0.w); xv[7]  = bhi(u0.w);
        xv[8]  = blo(u1.x); xv[9]  = bhi(u1.x); xv[10] = blo(u1.y); xv[11] = bhi(u1.y);
        xv[12] = blo(u1.z); xv[13] = bhi(u1.z); xv[14] = blo(u1.w); xv[15] = bhi(u1.w);
        #pragma unroll
        for (int j = 0; j < 16; j++)
            xv[j] = fmaxf(xv[j] * A[kc + j] + B[kc + j], 0.f);   // BN + ReLU
        unsigned hi[8], lo[8];
        #pragma unroll
        for (int i = 0; i < 8; i++) {
            unsigned short h0 = bf16r(xv[2 * i]), h1 = bf16r(xv[2 * i + 1]);
            float l0 = xv[2 * i]     - __uint_as_float(((unsigned)h0) << 16);
            float l1 = xv[2 * i + 1] - __uint_as_float(((unsigned)h1) << 16);
            hi[i] = (unsigned)h0 | ((unsigned)h1 << 16);
            lo[i] = bf16pair(l0, l1);
        }
        uint4* ph = (uint4*)&hs_s[nd * XSS + kc];
        ph[0] = make_uint4(hi[0], hi[1], hi[2], hi[3]);
        ph[1] = make_uint4(hi[4], hi[5], hi[6], hi[7]);
        uint4* pl = (uint4*)&hs_s[(nd + 32) * XSS + kc];
        pl[0] = make_uint4(lo[0], lo[1], lo[2], lo[3]);
        pl[1] = make_uint4(lo[4], lo[5], lo[6], lo[7]);
    }
    __syncthreads();
    int lane = threadIdx.x & 63;
    int lm = lane & 15, q = lane >> 4;
    int w = threadIdx.x >> 6;
    f32x4 acc[2];
    acc[0] = (f32x4)0.f; acc[1] = (f32x4)0.f;
    #pragma unroll
    for (int ks = 0; ks < 4; ks++) {
        int k0 = ks * 32 + q * 8;
        short8 ah0 = *(const short8*)&hs_s[(lm)      * XSS + k0];
        short8 ah1 = *(const short8*)&hs_s[(16 + lm) * XSS + k0];
        short8 al0 = *(const short8*)&hs_s[(32 + lm) * XSS + k0];
        short8 al1 = *(const short8*)&hs_s[(48 + lm) * XSS + k0];
        short8 bfr = *(const short8*)(WT2 + (size_t)(w * 16 + lm) * WTS + k0);
        acc[0] = __builtin_amdgcn_mfma_f32_16x16x32_bf16(al0, bfr, acc[0], 0, 0, 0);
        acc[0] = __builtin_amdgcn_mfma_f32_16x16x32_bf16(ah0, bfr, acc[0], 0, 0, 0);
        acc[1] = __builtin_amdgcn_mfma_f32_16x16x32_bf16(al1, bfr, acc[1], 0, 0, 0);
        acc[1] = __builtin_amdgcn_mfma_f32_16x16x32_bf16(ah1, bfr, acc[1], 0, 0, 0);
    }
    if (w < 2) {
        int ch = w * 16 + lm;                      // Wl2 col 0..31
        float bv = bl2[ch];
        #pragma unroll
        for (int mt = 0; mt < 2; mt++)
            #pragma unroll
            for (int r = 0; r < 4; r++) {
                int node = n0g + mt * 16 + q * 4 + r;
                float val = acc[mt][r] + bv;
                float pv = __shfl_xor(val, 1);
                if ((lm & 1) == 0 && node < NNODES)
                    xlb2[(size_t)node * 16 + (ch >> 1)] = bf16pair(val, pv);
            }
    } else {
        int ch = (w - 2) * 16 + lm;                // Wr2 col 0..31
        float bv = br2[ch];
        #pragma unroll
        for (int mt = 0; mt < 2; mt++)
            #pragma unroll
            for (int r = 0; r < 4; r++) {
                int node = n0g + mt * 16 + q * 4 + r;
                if (node < NNODES)
                    xr2[(size_t)node * HID + ch] = acc[mt][r] + bv;
            }
    }
}

// ---------------- conv2 fused edge phase + BN + classifier ------------------
// r3-proven strided persistent mapping; decoupled sc/xv pipelines (5/3).
__global__ __launch_bounds__(256) void k_edge2(
    const unsigned* __restrict__ xlb2, const float* __restrict__ xr2,
    const int* __restrict__ rowptr, const unsigned* __restrict__ cpack,
    const float* __restrict__ We2, const float* __restrict__ att2,
    const float* __restrict__ bias2,
    const float* __restrict__ g2, const float* __restrict__ b2,
    const float* __restrict__ m2, const float* __restrict__ v2,
    const float* __restrict__ W, const float* __restrict__ b,
    float* __restrict__ y) {
    int lane = threadIdx.x & 63;
    int q = lane & 7, s = lane >> 3;
    int node = blockIdx.x * 4 + (threadIdx.x >> 6);
    if (node >= NNODES) return;
    const int WV = EB2 * 4;
    const float C6 = 0.6f * L2E, C4 = 0.4f * L2E;
    float4 we = ((const float4*)We2)[q];
    float4 av4 = ((const float4*)att2)[q];
    float4 aA = make_float4(av4.x * C6, av4.y * C6, av4.z * C6, av4.w * C6);
    float4 aB = make_float4(av4.x * C4, av4.y * C4, av4.z * C4, av4.w * C4);
    // fold BN: h = (a*rd + bias - m)*sc + bb = (a*rd)*sA + sB
    float4 gv = ((const float4*)g2)[q];
    float4 bv = ((const float4*)b2)[q];
    float4 mv = ((const float4*)m2)[q];
    float4 vv = ((const float4*)v2)[q];
    float4 bi = ((const float4*)bias2)[q];
    float4 sA, sB;
    sA.x = gv.x * rsqrtf(vv.x + BNEPS); sB.x = (bi.x - mv.x) * sA.x + bv.x;
    sA.y = gv.y * rsqrtf(vv.y + BNEPS); sB.y = (bi.y - mv.y) * sA.y + bv.y;
    sA.z = gv.z * rsqrtf(vv.z + BNEPS); sB.z = (bi.z - mv.z) * sA.z + bv.z;
    sA.w = gv.w * rsqrtf(vv.w + BNEPS); sB.w = (bi.w - mv.w) * sA.w + bv.w;
    float4 w0 = ((const float4*)W)[2 * q];         // ch 4q,4q+1 x {out0,out1}
    float4 w1 = ((const float4*)W)[2 * q + 1];     // ch 4q+2,4q+3
    float bb0 = b[0], bb1 = b[1];
    const uint2* xlv = (const uint2*)xlb2;         // row = 8 uint2 (32 ch)
    int r0 = rowptr[node], r1 = rowptr[node + 1];
    float4 xr0 = ((const float4*)xr2)[(size_t)node * 8 + q];
    for (;;) {
        int nn = node + WV;
        bool more = nn < NNODES;
        int nr0 = 0, nr1 = 0;
        float4 nxr0 = make_float4(0.f, 0.f, 0.f, 0.f);
        if (more) {                                // prefetch next node
            nr0 = rowptr[nn]; nr1 = rowptr[nn + 1];
            nxr0 = ((const float4*)xr2)[(size_t)nn * 8 + q];
        }
        float den = 0.f;
        float a0 = 0.f, a1 = 0.f, a2 = 0.f, a3 = 0.f;
        int nit = (r1 - r0 + 7) >> 3;
        int k = r0 + s;
        unsigned sc0 = cpack[k];
        unsigned sc1 = cpack[k + 8];
        unsigned sc2 = cpack[k + 16];
        unsigned sc3 = cpack[k + 24];
        unsigned sc4 = cpack[k + 32];
        uint2 xv0 = xlv[(size_t)(sc0 & 0xffffu) * 8 + q];
        uint2 xv1 = xlv[(size_t)(sc1 & 0xffffu) * 8 + q];
        uint2 xv2 = xlv[(size_t)(sc2 & 0xffffu) * 8 + q];
        for (int it = 0; it < nit; it++) {
            unsigned scn = cpack[k + 40];                      // sc for group it+5
            uint2 xvn = xlv[(size_t)(sc3 & 0xffffu) * 8 + q];  // gather group it+3
            bool ok = k < r1;
            float av = __uint_as_float(sc0 & 0xffff0000u);
            float x0 = blo(xv0.x), x1 = bhi(xv0.x), x2 = blo(xv0.y), x3 = bhi(xv0.y);
            float s0 = fmaf(av, we.x, x0 + xr0.x);
            float s1 = fmaf(av, we.y, x1 + xr0.y);
            float s2 = fmaf(av, we.z, x2 + xr0.z);
            float s3 = fmaf(av, we.w, x3 + xr0.w);
            float tA = s0 * aA.x;             tA = fmaf(fabsf(s0), aB.x, tA);
            tA = fmaf(s1, aA.y, tA);          tA = fmaf(fabsf(s1), aB.y, tA);
            float tB = s2 * aA.z;             tB = fmaf(fabsf(s2), aB.z, tB);
            tB = fmaf(s3, aA.w, tB);          tB = fmaf(fabsf(s3), aB.w, tB);
            float t = tA + tB;
            t += __shfl_xor(t, 1);
            t += __shfl_xor(t, 2);
            t += __shfl_xor(t, 4);                 // 8-lane group = full logit
            float e = ok ? EXP2F(t) : 0.f;
            den += e;
            a0 = fmaf(e, x0, a0); a1 = fmaf(e, x1, a1);
            a2 = fmaf(e, x2, a2); a3 = fmaf(e, x3, a3);
            k += 8;
            sc0 = sc1; sc1 = sc2; sc2 = sc3; sc3 = sc4; sc4 = scn;
            xv0 = xv1; xv1 = xv2; xv2 = xvn;
        }
        #pragma unroll
        for (int o = 8; o <= 32; o <<= 1) {        // merge 8 slots
            den += __shfl_xor(den, o);
            a0 += __shfl_xor(a0, o); a1 += __shfl_xor(a1, o);
            a2 += __shfl_xor(a2, o); a3 += __shfl_xor(a3, o);
        }
        float rd = 1.f / den;
        float h0 = fmaxf(fmaf(a0 * rd, sA.x, sB.x), 0.f);
        float h1 = fmaxf(fmaf(a1 * rd, sA.y, sB.y), 0.f);
        float h2 = fmaxf(fmaf(a2 * rd, sA.z, sB.z), 0.f);
        float h3 = fmaxf(fmaf(a3 * rd, sA.w, sB.w), 0.f);
        float u0 = h0 * w0.x + h1 * w0.z + h2 * w1.x + h3 * w1.z;
        float u1 = h0 * w0.y + h1 * w0.w + h2 * w1.y + h3 * w1.w;
        u0 += __shfl_xor(u0, 1); u0 += __shfl_xor(u0, 2); u0 += __shfl_xor(u0, 4);
        u1 += __shfl_xor(u1, 1); u1 += __shfl_xor(u1, 2); u1 += __shfl_xor(u1, 4);
        if (lane == 0) {
            y[(size_t)node * 2]     = u0 + bb0;
            y[(size_t)node * 2 + 1] = u1 + bb1;
        }
        if (!more) return;
        node = nn; r0 = nr0; r1 = nr1; xr0 = nxr0;
    }
}

extern "C" void kernel_launch(void* const* d_in, const int* in_sizes, int n_in,
                              void* d_out, int out_size, void* d_ws, size_t ws_size,
                              hipStream_t stream) {
    const float* x       = (const float*)d_in[0];
    const int*   ei      = (const int*)d_in[1];
    const float* ea      = (const float*)d_in[2];
    const float* c1_Wl   = (const float*)d_in[3];
    const float* c1_bl   = (const float*)d_in[4];
    const float* c1_Wr   = (const float*)d_in[5];
    const float* c1_br   = (const float*)d_in[6];
    const float* c1_We   = (const float*)d_in[7];
    const float* c1_att  = (const float*)d_in[8];
    const float* c1_bias = (const float*)d_in[9];
    const float* bn1_g   = (const float*)d_in[10];
    const float* bn1_b   = (const float*)d_in[11];
    const float* bn1_m   = (const float*)d_in[12];
    const float* bn1_v   = (const float*)d_in[13];
    const float* c2_Wl   = (const float*)d_in[14];
    const float* c2_bl   = (const float*)d_in[15];
    const float* c2_Wr   = (const float*)d_in[16];
    const float* c2_br   = (const float*)d_in[17];
    const float* c2_We   = (const float*)d_in[18];
    const float* c2_att  = (const float*)d_in[19];
    const float* c2_bias = (const float*)d_in[20];
    const float* bn2_g   = (const float*)d_in[21];
    const float* bn2_b   = (const float*)d_in[22];
    const float* bn2_m   = (const float*)d_in[23];
    const float* bn2_v   = (const float*)d_in[24];
    const float* clf_W   = (const float*)d_in[25];
    const float* clf_b   = (const float*)d_in[26];

    float* ws = (float*)d_ws;
    size_t off = 0;
    unsigned* XLb  = (unsigned*)(ws + off); off += (size_t)NNODES * 64;  // bf16x2
    unsigned* XRb  = (unsigned*)(ws + off); off += (size_t)NNODES * 64;  // bf16x2
    unsigned* OUT1b= (unsigned*)(ws + off); off += (size_t)NNODES * 64;  // bf16x2
    unsigned* XLb2 = (unsigned*)(ws + off); off += (size_t)NNODES * 16;  // bf16x2
    float*    XR2  = ws + off; off += (size_t)NNODES * HID;
    unsigned* CPACK= (unsigned*)(ws + off); off += (size_t)ETOT + 64;    // 4B/edge
    unsigned short* WT  = (unsigned short*)(ws + off); off += 256 * WTS / 2;
    unsigned short* WT2 = (unsigned short*)(ws + off); off += 64 * WTS / 2;
    int*      EOFF = (int*)(ws + off); off += NEDGES;
    int*      ROWP = (int*)(ws + off); off += NNODES + 16;
    int*      DEG  = (int*)(ws + off); off += NNODES;
    int*      BSUM = (int*)(ws + off); off += 256;
    int*      HIST = (int*)(ws + off); off += (size_t)NC * NNODES;  // zeroed by k_prep
    float*    MEANB= ws + off; off += 64;
    if (ws_size < off * sizeof(float)) return;  // workspace too small: fail loudly

    k_prep  <<<160, 256, 0, stream>>>(c1_Wl, c1_Wr, c2_Wl, c2_Wr, WT, WT2, HIST, MEANB);
    k_xf_eh <<<XFEB, 256, 0, stream>>>(x, c1_bl, c1_br, WT, XLb, XRb,
                                       ei, ea, HIST, EOFF, MEANB);
    k_red   <<<SCB, 256, 0, stream>>>(HIST, DEG, BSUM);
    k_rowp  <<<SCB, 256, 0, stream>>>(DEG, BSUM, ROWP);
    k_fill  <<<FEB + FLB + 1, 256, 0, stream>>>(ei, ea, ROWP, MEANB, HIST, EOFF, CPACK);
    k_edge1 <<<EB1, 256, 0, stream>>>(XLb, XRb, ROWP, CPACK, c1_We, c1_att, OUT1b);
    k_epi   <<<XFB2, 256, 0, stream>>>(OUT1b, c1_bias, bn1_g, bn1_b, bn1_m, bn1_v,
                                       WT2, c2_bl, c2_br, XLb2, XR2);
    k_edge2 <<<EB2, 256, 0, stream>>>(XLb2, XR2, ROWP, CPACK, c2_We, c2_att,
                                      c2_bias, bn2_g, bn2_b, bn2_m, bn2_v,
                                      clf_W, clf_b, (float*)d_out);
}